// Round 5
// baseline (551.686 us; speedup 1.0000x reference)
//
#include <hip/hip_runtime.h>
#include <math.h>

// ---------------------------------------------------------------------------
// GCN 165->32->16->2 + log_softmax, N=100k, E=3.2M.
//
// Round 5 (on top of round 4's partition+sort+gather structure):
//  - Feature-chunked gathers: hs stored blocked [chunk][N][8]; each chunk is
//    3.2MB -> L2-resident per XCD, gathers served at L2 (~34.5TB/s) instead
//    of L3 (~3.6TB/s measured ceiling in round 4).
//  - gemm1 (165->32) stages x in LDS with coalesced flat loads (stride-33
//    tile, bank-conflict-free) instead of per-thread scalar row reads.
//  - place: NPB=256 (391 buckets), EPB_B=8192 -> 84B avg chunks, ~4x less
//    cross-XCD line sharing on ebuf writes.
// hs = dinv*(in@W); agg[n] = hs[n] + sum_in hs[s];
// next-layer input relu(dinv*agg+b) fused into next GEMM's read.
// ---------------------------------------------------------------------------

constexpr int NT = 256;
constexpr int NPB = 256;       // nodes per bucket
constexpr int LOG_NPB = 8;
constexpr int MAXBUK = 512;
constexpr int EPB_A = 8192;    // edges per block, count pass
constexpr int EPB_B = 8192;    // edges per block, place pass

__global__ __launch_bounds__(NT) void count_kernel(const int* __restrict__ dst,
                                                   int* __restrict__ gcnt,
                                                   int E, int nbuk) {
    __shared__ int lh[MAXBUK];
    for (int i = threadIdx.x; i < nbuk; i += NT) lh[i] = 0;
    __syncthreads();
    int base = blockIdx.x * EPB_A;
#pragma unroll
    for (int i = 0; i < EPB_A / NT; i++) {
        int e = base + i * NT + threadIdx.x;
        if (e < E) atomicAdd(&lh[dst[e] >> LOG_NPB], 1);
    }
    __syncthreads();
    for (int i = threadIdx.x; i < nbuk; i += NT) {
        int v = lh[i];
        if (v) atomicAdd(&gcnt[i], v);
    }
}

__global__ __launch_bounds__(MAXBUK) void scan_kernel(const int* __restrict__ gcnt,
                                                      int* __restrict__ bptr,
                                                      int* __restrict__ cursor,
                                                      int nbuk, int E) {
    __shared__ int s[MAXBUK];
    int t = threadIdx.x;
    int v = (t < nbuk) ? gcnt[t] : 0;
    s[t] = v;
    __syncthreads();
    for (int off = 1; off < MAXBUK; off <<= 1) {
        int a = (t >= off) ? s[t - off] : 0;
        __syncthreads();
        s[t] += a;
        __syncthreads();
    }
    if (t < nbuk) { int excl = s[t] - v; bptr[t] = excl; cursor[t] = excl; }
    if (t == 0) bptr[nbuk] = E;
}

__global__ __launch_bounds__(NT) void place_kernel(const int* __restrict__ src,
                                                   const int* __restrict__ dst,
                                                   int* __restrict__ cursor,
                                                   unsigned* __restrict__ ebuf,
                                                   int E, int nbuk) {
    __shared__ int lh[MAXBUK];
    __shared__ int lbase[MAXBUK];
    for (int i = threadIdx.x; i < nbuk; i += NT) lh[i] = 0;
    __syncthreads();
    constexpr int EPT = EPB_B / NT;  // 32
    unsigned pk[EPT];
    unsigned bl[EPT];
    int base = blockIdx.x * EPB_B;
#pragma unroll
    for (int i = 0; i < EPT; i++) {
        int e = base + i * NT + threadIdx.x;
        if (e < E) {
            int s = src[e], d = dst[e];
            int b = d >> LOG_NPB;
            int lp = atomicAdd(&lh[b], 1);
            pk[i] = ((unsigned)(d & (NPB - 1)) << 24) | (unsigned)s;
            bl[i] = ((unsigned)b << 16) | (unsigned)lp;
        } else {
            bl[i] = 0xFFFFFFFFu;
        }
    }
    __syncthreads();
    for (int i = threadIdx.x; i < nbuk; i += NT) {
        int v = lh[i];
        if (v) lbase[i] = atomicAdd(&cursor[i], v);
    }
    __syncthreads();
#pragma unroll
    for (int i = 0; i < EPT; i++) {
        if (bl[i] != 0xFFFFFFFFu) {
            int b = (int)(bl[i] >> 16);
            int lp = (int)(bl[i] & 0xFFFFu);
            ebuf[lbase[b] + lp] = pk[i];
        }
    }
}

// One block per bucket (256 nodes): in-LDS counting sort of (local<<24)|src
// into node-ordered esrc; emits rowptr and dinv. Output range block-exclusive.
__global__ __launch_bounds__(NT) void sort_kernel(
    const unsigned* __restrict__ ebuf, const int* __restrict__ bptr,
    int* __restrict__ esrc, int* __restrict__ rowptr,
    float* __restrict__ dinv, int N, int E) {
    __shared__ int cnt[NPB];
    __shared__ int ofs[NPB];
    __shared__ int cur[NPB];
    int tid = threadIdx.x;
    int b = blockIdx.x;
    cnt[tid] = 0;
    __syncthreads();
    int e0 = bptr[b], e1 = bptr[b + 1];
    for (int i = e0 + tid; i < e1; i += NT)
        atomicAdd(&cnt[ebuf[i] >> 24], 1);
    __syncthreads();
    ofs[tid] = cnt[tid];
    __syncthreads();
    for (int off = 1; off < NPB; off <<= 1) {
        int a = (tid >= off) ? ofs[tid - off] : 0;
        __syncthreads();
        ofs[tid] += a;
        __syncthreads();
    }
    {
        int excl = ofs[tid] - cnt[tid];
        cur[tid] = excl;
        int n = b * NPB + tid;
        if (n < N) {
            rowptr[n] = e0 + excl;
            dinv[n] = rsqrtf((float)cnt[tid] + 1.0f);
        }
    }
    if (b == 0 && tid == 0) rowptr[N] = E;
    __syncthreads();
    for (int i = e0 + tid; i < e1; i += NT) {
        unsigned p = ebuf[i];
        int l = (int)(p >> 24);
        int pos = atomicAdd(&cur[l], 1);
        esrc[e0 + pos] = (int)(p & 0xFFFFFFu);
    }
}

// Layer 1 GEMM 165->32, LDS-staged x (coalesced), blocked hs output
// hs[ch][N][8] for ch in 0..3.
__global__ __launch_bounds__(NT) void gemm1_kernel(
    const float* __restrict__ in, const float* __restrict__ W,
    const float* __restrict__ dinv, float* __restrict__ hs, int N) {
    constexpr int DIN = 165, DOUT = 32, KT = 33;  // 165 = 5*33
    __shared__ float Ws[DIN * DOUT];   // 21.1 KB
    __shared__ float xs[NT * KT];      // 33.8 KB, stride 33 (odd) -> bank-clean
    int tid = threadIdx.x;
    for (int i = tid; i < DIN * DOUT; i += NT) Ws[i] = W[i];
    int n0 = blockIdx.x * NT;
    int n = n0 + tid;
    float acc[DOUT];
#pragma unroll
    for (int d = 0; d < DOUT; d++) acc[d] = 0.f;
    for (int t = 0; t < DIN / KT; t++) {
        int k0 = t * KT;
        __syncthreads();
        for (int f = tid; f < NT * KT; f += NT) {
            int r = f / KT, kk = f - r * KT;
            int nn = n0 + r;
            xs[r * KT + kk] = (nn < N) ? in[(size_t)nn * DIN + k0 + kk] : 0.f;
        }
        __syncthreads();
#pragma unroll
        for (int kk = 0; kk < KT; kk++) {
            float xv = xs[tid * KT + kk];
#pragma unroll
            for (int d = 0; d < DOUT; d++)
                acc[d] = fmaf(xv, Ws[(k0 + kk) * DOUT + d], acc[d]);
        }
    }
    if (n >= N) return;
    float dv = dinv[n];
#pragma unroll
    for (int ch = 0; ch < 4; ch++) {
        float4 h0 = {dv * acc[ch * 8 + 0], dv * acc[ch * 8 + 1],
                     dv * acc[ch * 8 + 2], dv * acc[ch * 8 + 3]};
        float4 h1 = {dv * acc[ch * 8 + 4], dv * acc[ch * 8 + 5],
                     dv * acc[ch * 8 + 6], dv * acc[ch * 8 + 7]};
        float4* hp = (float4*)(hs + ((size_t)ch * N + n) * 8);
        hp[0] = h0;
        hp[1] = h1;
    }
}

// Mid GEMMs: thread-per-node, feature = relu(dinv*in + bprev).
// NCH: number of 8-wide output chunks (blocked hs layout). NCH=0 -> row-major.
template <int DIN, int DOUT, int NCH>
__global__ __launch_bounds__(NT) void gemm_kernel(
    const float* __restrict__ in, const float* __restrict__ bprev,
    const float* __restrict__ W, const float* __restrict__ dinv,
    float* __restrict__ hs, int N) {
    __shared__ float Ws[DIN * DOUT];
    __shared__ float bs[DIN];
    int tid = threadIdx.x;
    for (int i = tid; i < DIN * DOUT; i += NT) Ws[i] = W[i];
    for (int i = tid; i < DIN; i += NT) bs[i] = bprev[i];
    __syncthreads();
    int n = blockIdx.x * NT + tid;
    if (n >= N) return;
    float dv = dinv[n];
    float acc[DOUT];
#pragma unroll
    for (int d = 0; d < DOUT; d++) acc[d] = 0.f;
    const float* row = in + (size_t)n * DIN;
    for (int k = 0; k < DIN; k++) {
        float xv = fmaxf(fmaf(dv, row[k], bs[k]), 0.f);
#pragma unroll
        for (int d = 0; d < DOUT; d++) acc[d] = fmaf(xv, Ws[k * DOUT + d], acc[d]);
    }
    if constexpr (NCH > 0) {
#pragma unroll
        for (int ch = 0; ch < NCH; ch++) {
            float4 h0 = {dv * acc[ch * 8 + 0], dv * acc[ch * 8 + 1],
                         dv * acc[ch * 8 + 2], dv * acc[ch * 8 + 3]};
            float4 h1 = {dv * acc[ch * 8 + 4], dv * acc[ch * 8 + 5],
                         dv * acc[ch * 8 + 6], dv * acc[ch * 8 + 7]};
            float4* hp = (float4*)(hs + ((size_t)ch * N + n) * 8);
            hp[0] = h0;
            hp[1] = h1;
        }
    } else {
        float* hp = hs + (size_t)n * DOUT;
#pragma unroll
        for (int d = 0; d < DOUT; d++) hp[d] = dv * acc[d];
    }
}

// One feature chunk (8 floats/node = 2 float4 lanes). hsC is this chunk's
// [N][8] block (L2-resident 3.2MB). aggC = (float4*)agg + ch*2; row stride
// OS float4s. 2 lanes per node, reg accumulation, unrolled x4.
template <int OS>
__global__ __launch_bounds__(NT) void gather_chunk_kernel(
    const float* __restrict__ hsC, const int* __restrict__ esrc,
    const int* __restrict__ rowptr, float4* __restrict__ aggC, int N) {
    int gid = blockIdx.x * NT + threadIdx.x;
    int n = gid >> 1;
    int c = gid & 1;
    if (n >= N) return;
    int j = rowptr[n];
    int end = rowptr[n + 1];
    const float4* base = (const float4*)hsC;
    float4 acc = base[(size_t)n * 2 + c];  // self-loop message
    for (; j + 4 <= end; j += 4) {
        int s0 = esrc[j], s1 = esrc[j + 1], s2 = esrc[j + 2], s3 = esrc[j + 3];
        float4 v0 = base[(size_t)s0 * 2 + c];
        float4 v1 = base[(size_t)s1 * 2 + c];
        float4 v2 = base[(size_t)s2 * 2 + c];
        float4 v3 = base[(size_t)s3 * 2 + c];
        acc.x += v0.x + v1.x + v2.x + v3.x;
        acc.y += v0.y + v1.y + v2.y + v3.y;
        acc.z += v0.z + v1.z + v2.z + v3.z;
        acc.w += v0.w + v1.w + v2.w + v3.w;
    }
    for (; j < end; j++) {
        float4 v = base[(size_t)esrc[j] * 2 + c];
        acc.x += v.x; acc.y += v.y; acc.z += v.z; acc.w += v.w;
    }
    aggC[(size_t)n * OS + c] = acc;
}

// Layer 3 gather (DOUT=2, hs3 0.8MB L2-resident) + bias + log_softmax.
__global__ __launch_bounds__(NT) void final_kernel(
    const float* __restrict__ hs3, const int* __restrict__ esrc,
    const int* __restrict__ rowptr, const float* __restrict__ dinv,
    const float* __restrict__ b, float* __restrict__ out, int N) {
    int n = blockIdx.x * NT + threadIdx.x;
    if (n >= N) return;
    int j = rowptr[n];
    int end = rowptr[n + 1];
    const float2* h2 = (const float2*)hs3;
    float2 acc = h2[n];
    for (; j + 4 <= end; j += 4) {
        float2 v0 = h2[esrc[j]], v1 = h2[esrc[j + 1]];
        float2 v2 = h2[esrc[j + 2]], v3 = h2[esrc[j + 3]];
        acc.x += v0.x + v1.x + v2.x + v3.x;
        acc.y += v0.y + v1.y + v2.y + v3.y;
    }
    for (; j < end; j++) {
        float2 v = h2[esrc[j]];
        acc.x += v.x; acc.y += v.y;
    }
    float dv = dinv[n];
    float z0 = fmaf(dv, acc.x, b[0]);
    float z1 = fmaf(dv, acc.y, b[1]);
    float m = fmaxf(z0, z1);
    float lse = m + logf(expf(z0 - m) + expf(z1 - m));
    out[(size_t)n * 2 + 0] = z0 - lse;
    out[(size_t)n * 2 + 1] = z1 - lse;
}

extern "C" void kernel_launch(void* const* d_in, const int* in_sizes, int n_in,
                              void* d_out, int out_size, void* d_ws, size_t ws_size,
                              hipStream_t stream) {
    const float* x  = (const float*)d_in[0];
    const int*   ei = (const int*)d_in[1];
    const float* W1 = (const float*)d_in[2];
    const float* b1 = (const float*)d_in[3];
    const float* W2 = (const float*)d_in[4];
    const float* b2 = (const float*)d_in[5];
    const float* W3 = (const float*)d_in[6];
    const float* b3 = (const float*)d_in[7];
    float* out = (float*)d_out;

    const int N = in_sizes[0] / 165;  // 100000
    const int E = in_sizes[1] / 2;    // 3200000
    const int* src = ei;
    const int* dst = ei + E;
    const int nbuk = (N + NPB - 1) >> LOG_NPB;  // 391
    const int NB = (N + NT - 1) / NT;           // 391

    char* p = (char*)d_ws;
    int* gcnt      = (int*)p;      p += (size_t)MAXBUK * 4;
    int* bptr      = (int*)p;      p += (size_t)(MAXBUK + 1) * 4;
    int* cursor    = (int*)p;      p += (size_t)MAXBUK * 4;
    unsigned* ebuf = (unsigned*)p; p += (size_t)E * 4;
    int* esrc      = (int*)p;      p += (size_t)E * 4;
    int* rowptr    = (int*)p;      p += (size_t)(N + 1) * 4;
    float* dinv    = (float*)p;    p += (size_t)N * 4;
    float* hs1     = (float*)p;    p += (size_t)N * 32 * 4;  // blocked [4][N][8]
    float* agg1    = (float*)p;    p += (size_t)N * 32 * 4;  // row-major [N][32]
    float* hs3     = (float*)p;    p += (size_t)N * 2 * 4;
    float* hs2     = hs1;                    // blocked [2][N][8]; hs1 dead then
    float* agg2    = hs1 + (size_t)N * 16;   // row-major [N][16]

    hipMemsetAsync(gcnt, 0, (size_t)MAXBUK * sizeof(int), stream);
    count_kernel<<<(E + EPB_A - 1) / EPB_A, NT, 0, stream>>>(dst, gcnt, E, nbuk);
    scan_kernel<<<1, MAXBUK, 0, stream>>>(gcnt, bptr, cursor, nbuk, E);
    place_kernel<<<(E + EPB_B - 1) / EPB_B, NT, 0, stream>>>(src, dst, cursor, ebuf, E, nbuk);
    sort_kernel<<<nbuk, NT, 0, stream>>>(ebuf, bptr, esrc, rowptr, dinv, N, E);

    const int GB = ((size_t)N * 2 + NT - 1) / NT;  // blocks per gather chunk

    // Layer 1: 165 -> 32, 4 L2-resident chunks
    gemm1_kernel<<<NB, NT, 0, stream>>>(x, W1, dinv, hs1, N);
    for (int ch = 0; ch < 4; ch++) {
        gather_chunk_kernel<8><<<GB, NT, 0, stream>>>(
            hs1 + (size_t)ch * N * 8, esrc, rowptr, (float4*)agg1 + ch * 2, N);
    }

    // Layer 2: 32 -> 16, 2 L2-resident chunks
    gemm_kernel<32, 16, 2><<<NB, NT, 0, stream>>>(agg1, b1, W2, dinv, hs2, N);
    for (int ch = 0; ch < 2; ch++) {
        gather_chunk_kernel<4><<<GB, NT, 0, stream>>>(
            hs2 + (size_t)ch * N * 8, esrc, rowptr, (float4*)agg2 + ch * 2, N);
    }

    // Layer 3: 16 -> 2, gather + bias + log_softmax fused
    gemm_kernel<16, 2, 0><<<NB, NT, 0, stream>>>(agg2, b2, W3, dinv, hs3, N);
    final_kernel<<<NB, NT, 0, stream>>>(hs3, esrc, rowptr, dinv, b3, out, N);
}

// Round 6
// 525.482 us; speedup vs baseline: 1.0499x; 1.0499x over previous
//
#include <hip/hip_runtime.h>
#include <math.h>

// ---------------------------------------------------------------------------
// GCN 165->32->16->2 + log_softmax, N=100k, E=3.2M.
//
// Round 6:
//  - gemm1 v2: 256 thr / 128 nodes (2 thr/node, 16 outs each), per-tile W
//    slice + x tile staged in LDS (21KB total, was 55KB -> occupancy 15.6%
//    and 113us in round 5). 782 blocks, ~12 waves/CU.
//  - place: EPT back to 16 (EPB_B=4096); round 5's EPT=32 meant 64 VGPRs of
//    unrolled arrays (spill risk).
//  - gemm2/3: float4 row loads (rows 128B/64B, aligned) instead of scalar.
//  - keep: bucket partition + in-LDS counting sort + feature-chunked
//    L2-resident gathers (hs blocked [ch][N][8], 3.2MB/chunk).
// hs = dinv*(in@W); agg[n] = hs[n] + sum_in hs[s];
// next-layer input relu(dinv*agg+b) fused into next GEMM's read.
// ---------------------------------------------------------------------------

constexpr int NT = 256;
constexpr int NPB = 256;       // nodes per bucket (partition)
constexpr int LOG_NPB = 8;
constexpr int MAXBUK = 512;
constexpr int EPB_A = 8192;    // edges per block, count pass
constexpr int EPB_B = 4096;    // edges per block, place pass

__global__ __launch_bounds__(NT) void count_kernel(const int* __restrict__ dst,
                                                   int* __restrict__ gcnt,
                                                   int E, int nbuk) {
    __shared__ int lh[MAXBUK];
    for (int i = threadIdx.x; i < nbuk; i += NT) lh[i] = 0;
    __syncthreads();
    int base = blockIdx.x * EPB_A;
#pragma unroll
    for (int i = 0; i < EPB_A / NT; i++) {
        int e = base + i * NT + threadIdx.x;
        if (e < E) atomicAdd(&lh[dst[e] >> LOG_NPB], 1);
    }
    __syncthreads();
    for (int i = threadIdx.x; i < nbuk; i += NT) {
        int v = lh[i];
        if (v) atomicAdd(&gcnt[i], v);
    }
}

__global__ __launch_bounds__(MAXBUK) void scan_kernel(const int* __restrict__ gcnt,
                                                      int* __restrict__ bptr,
                                                      int* __restrict__ cursor,
                                                      int nbuk, int E) {
    __shared__ int s[MAXBUK];
    int t = threadIdx.x;
    int v = (t < nbuk) ? gcnt[t] : 0;
    s[t] = v;
    __syncthreads();
    for (int off = 1; off < MAXBUK; off <<= 1) {
        int a = (t >= off) ? s[t - off] : 0;
        __syncthreads();
        s[t] += a;
        __syncthreads();
    }
    if (t < nbuk) { int excl = s[t] - v; bptr[t] = excl; cursor[t] = excl; }
    if (t == 0) bptr[nbuk] = E;
}

__global__ __launch_bounds__(NT) void place_kernel(const int* __restrict__ src,
                                                   const int* __restrict__ dst,
                                                   int* __restrict__ cursor,
                                                   unsigned* __restrict__ ebuf,
                                                   int E, int nbuk) {
    __shared__ int lh[MAXBUK];
    __shared__ int lbase[MAXBUK];
    for (int i = threadIdx.x; i < nbuk; i += NT) lh[i] = 0;
    __syncthreads();
    constexpr int EPT = EPB_B / NT;  // 16
    unsigned pk[EPT];
    unsigned bl[EPT];
    int base = blockIdx.x * EPB_B;
#pragma unroll
    for (int i = 0; i < EPT; i++) {
        int e = base + i * NT + threadIdx.x;
        if (e < E) {
            int s = src[e], d = dst[e];
            int b = d >> LOG_NPB;
            int lp = atomicAdd(&lh[b], 1);
            pk[i] = ((unsigned)(d & (NPB - 1)) << 24) | (unsigned)s;
            bl[i] = ((unsigned)b << 16) | (unsigned)lp;
        } else {
            bl[i] = 0xFFFFFFFFu;
        }
    }
    __syncthreads();
    for (int i = threadIdx.x; i < nbuk; i += NT) {
        int v = lh[i];
        if (v) lbase[i] = atomicAdd(&cursor[i], v);
    }
    __syncthreads();
#pragma unroll
    for (int i = 0; i < EPT; i++) {
        if (bl[i] != 0xFFFFFFFFu) {
            int b = (int)(bl[i] >> 16);
            int lp = (int)(bl[i] & 0xFFFFu);
            ebuf[lbase[b] + lp] = pk[i];
        }
    }
}

// One block per bucket (256 nodes): in-LDS counting sort of (local<<24)|src
// into node-ordered esrc; emits rowptr and dinv. Output range block-exclusive.
__global__ __launch_bounds__(NT) void sort_kernel(
    const unsigned* __restrict__ ebuf, const int* __restrict__ bptr,
    int* __restrict__ esrc, int* __restrict__ rowptr,
    float* __restrict__ dinv, int N, int E) {
    __shared__ int cnt[NPB];
    __shared__ int ofs[NPB];
    __shared__ int cur[NPB];
    int tid = threadIdx.x;
    int b = blockIdx.x;
    cnt[tid] = 0;
    __syncthreads();
    int e0 = bptr[b], e1 = bptr[b + 1];
    for (int i = e0 + tid; i < e1; i += NT)
        atomicAdd(&cnt[ebuf[i] >> 24], 1);
    __syncthreads();
    ofs[tid] = cnt[tid];
    __syncthreads();
    for (int off = 1; off < NPB; off <<= 1) {
        int a = (tid >= off) ? ofs[tid - off] : 0;
        __syncthreads();
        ofs[tid] += a;
        __syncthreads();
    }
    {
        int excl = ofs[tid] - cnt[tid];
        cur[tid] = excl;
        int n = b * NPB + tid;
        if (n < N) {
            rowptr[n] = e0 + excl;
            dinv[n] = rsqrtf((float)cnt[tid] + 1.0f);
        }
    }
    if (b == 0 && tid == 0) rowptr[N] = E;
    __syncthreads();
    for (int i = e0 + tid; i < e1; i += NT) {
        unsigned p = ebuf[i];
        int l = (int)(p >> 24);
        int pos = atomicAdd(&cur[l], 1);
        esrc[e0 + pos] = (int)(p & 0xFFFFFFu);
    }
}

// Layer 1 GEMM 165->32. 256 threads handle 128 nodes: 2 threads/node, 16
// outputs each. Per k-tile (KT=33, 5 tiles): stage W slice (4.2KB) + x tile
// (16.9KB) -> 21KB LDS. Blocked output hs[ch][N][8], ch=0..3.
__global__ __launch_bounds__(NT) void gemm1_kernel(
    const float* __restrict__ in, const float* __restrict__ W,
    const float* __restrict__ dinv, float* __restrict__ hs, int N) {
    constexpr int DIN = 165, DOUT = 32, KT = 33, NN = 128;
    __shared__ float Wt[KT * DOUT];   // 4.2 KB (tile slice of W)
    __shared__ float xs[NN * KT];     // 16.9 KB, stride 33 -> bank-clean
    int tid = threadIdx.x;
    int nl = tid >> 1;       // local node 0..127
    int c = tid & 1;         // output half: features [c*16, c*16+16)
    int n0 = blockIdx.x * NN;
    float acc[16];
#pragma unroll
    for (int d = 0; d < 16; d++) acc[d] = 0.f;
    for (int t = 0; t < DIN / KT; t++) {
        int k0 = t * KT;
        __syncthreads();
        // W slice: contiguous copy of KT*32 floats starting at W[k0*32]
        for (int i = tid; i < KT * DOUT; i += NT) Wt[i] = W[k0 * DOUT + i];
        // x tile: rows n0..n0+127, cols k0..k0+32
        for (int f = tid; f < NN * KT; f += NT) {
            int r = f / KT, kk = f - r * KT;
            int nn = n0 + r;
            xs[f] = (nn < N) ? in[(size_t)nn * DIN + k0 + kk] : 0.f;
        }
        __syncthreads();
#pragma unroll
        for (int kk = 0; kk < KT; kk++) {
            float xv = xs[nl * KT + kk];
#pragma unroll
            for (int d = 0; d < 16; d++)
                acc[d] = fmaf(xv, Wt[kk * DOUT + c * 16 + d], acc[d]);
        }
    }
    int n = n0 + nl;
    if (n >= N) return;
    float dv = dinv[n];
#pragma unroll
    for (int chh = 0; chh < 2; chh++) {
        int ch = c * 2 + chh;  // global 8-feature chunk index
        float4 h0 = {dv * acc[chh * 8 + 0], dv * acc[chh * 8 + 1],
                     dv * acc[chh * 8 + 2], dv * acc[chh * 8 + 3]};
        float4 h1 = {dv * acc[chh * 8 + 4], dv * acc[chh * 8 + 5],
                     dv * acc[chh * 8 + 6], dv * acc[chh * 8 + 7]};
        float4* hp = (float4*)(hs + ((size_t)ch * N + n) * 8);
        hp[0] = h0;
        hp[1] = h1;
    }
}

// Mid GEMMs: thread-per-node, float4 row loads, feature = relu(dinv*in+bprev).
// NCH>0: blocked hs output [NCH][N][8]. NCH=0: row-major (float2 for DOUT=2).
template <int DIN, int DOUT, int NCH>
__global__ __launch_bounds__(NT) void gemm_kernel(
    const float* __restrict__ in, const float* __restrict__ bprev,
    const float* __restrict__ W, const float* __restrict__ dinv,
    float* __restrict__ hs, int N) {
    __shared__ float Ws[DIN * DOUT];
    __shared__ float bs[DIN];
    int tid = threadIdx.x;
    for (int i = tid; i < DIN * DOUT; i += NT) Ws[i] = W[i];
    for (int i = tid; i < DIN; i += NT) bs[i] = bprev[i];
    __syncthreads();
    int n = blockIdx.x * NT + tid;
    if (n >= N) return;
    float dv = dinv[n];
    float acc[DOUT];
#pragma unroll
    for (int d = 0; d < DOUT; d++) acc[d] = 0.f;
    const float4* row4 = (const float4*)(in + (size_t)n * DIN);
#pragma unroll
    for (int q = 0; q < DIN / 4; q++) {
        float4 v = row4[q];
        float xv[4] = {v.x, v.y, v.z, v.w};
#pragma unroll
        for (int j = 0; j < 4; j++) {
            int k = q * 4 + j;
            float f = fmaxf(fmaf(dv, xv[j], bs[k]), 0.f);
#pragma unroll
            for (int d = 0; d < DOUT; d++) acc[d] = fmaf(f, Ws[k * DOUT + d], acc[d]);
        }
    }
    if constexpr (NCH > 0) {
#pragma unroll
        for (int ch = 0; ch < NCH; ch++) {
            float4 h0 = {dv * acc[ch * 8 + 0], dv * acc[ch * 8 + 1],
                         dv * acc[ch * 8 + 2], dv * acc[ch * 8 + 3]};
            float4 h1 = {dv * acc[ch * 8 + 4], dv * acc[ch * 8 + 5],
                         dv * acc[ch * 8 + 6], dv * acc[ch * 8 + 7]};
            float4* hp = (float4*)(hs + ((size_t)ch * N + n) * 8);
            hp[0] = h0;
            hp[1] = h1;
        }
    } else {
        float2 h = {dv * acc[0], dv * acc[1]};
        *(float2*)(hs + (size_t)n * 2) = h;
    }
}

// One feature chunk (8 floats/node = 2 float4 lanes). hsC = chunk's [N][8]
// block (3.2MB, L2-resident). aggC row stride OS float4s. Unrolled x4.
template <int OS>
__global__ __launch_bounds__(NT) void gather_chunk_kernel(
    const float* __restrict__ hsC, const int* __restrict__ esrc,
    const int* __restrict__ rowptr, float4* __restrict__ aggC, int N) {
    int gid = blockIdx.x * NT + threadIdx.x;
    int n = gid >> 1;
    int c = gid & 1;
    if (n >= N) return;
    int j = rowptr[n];
    int end = rowptr[n + 1];
    const float4* base = (const float4*)hsC;
    float4 acc = base[(size_t)n * 2 + c];  // self-loop message
    for (; j + 4 <= end; j += 4) {
        int s0 = esrc[j], s1 = esrc[j + 1], s2 = esrc[j + 2], s3 = esrc[j + 3];
        float4 v0 = base[(size_t)s0 * 2 + c];
        float4 v1 = base[(size_t)s1 * 2 + c];
        float4 v2 = base[(size_t)s2 * 2 + c];
        float4 v3 = base[(size_t)s3 * 2 + c];
        acc.x += v0.x + v1.x + v2.x + v3.x;
        acc.y += v0.y + v1.y + v2.y + v3.y;
        acc.z += v0.z + v1.z + v2.z + v3.z;
        acc.w += v0.w + v1.w + v2.w + v3.w;
    }
    for (; j < end; j++) {
        float4 v = base[(size_t)esrc[j] * 2 + c];
        acc.x += v.x; acc.y += v.y; acc.z += v.z; acc.w += v.w;
    }
    aggC[(size_t)n * OS + c] = acc;
}

// Layer 3 gather (hs3 0.8MB, L2-resident) + bias + log_softmax.
__global__ __launch_bounds__(NT) void final_kernel(
    const float* __restrict__ hs3, const int* __restrict__ esrc,
    const int* __restrict__ rowptr, const float* __restrict__ dinv,
    const float* __restrict__ b, float* __restrict__ out, int N) {
    int n = blockIdx.x * NT + threadIdx.x;
    if (n >= N) return;
    int j = rowptr[n];
    int end = rowptr[n + 1];
    const float2* h2 = (const float2*)hs3;
    float2 acc = h2[n];
    for (; j + 4 <= end; j += 4) {
        float2 v0 = h2[esrc[j]], v1 = h2[esrc[j + 1]];
        float2 v2 = h2[esrc[j + 2]], v3 = h2[esrc[j + 3]];
        acc.x += v0.x + v1.x + v2.x + v3.x;
        acc.y += v0.y + v1.y + v2.y + v3.y;
    }
    for (; j < end; j++) {
        float2 v = h2[esrc[j]];
        acc.x += v.x; acc.y += v.y;
    }
    float dv = dinv[n];
    float z0 = fmaf(dv, acc.x, b[0]);
    float z1 = fmaf(dv, acc.y, b[1]);
    float m = fmaxf(z0, z1);
    float lse = m + logf(expf(z0 - m) + expf(z1 - m));
    out[(size_t)n * 2 + 0] = z0 - lse;
    out[(size_t)n * 2 + 1] = z1 - lse;
}

extern "C" void kernel_launch(void* const* d_in, const int* in_sizes, int n_in,
                              void* d_out, int out_size, void* d_ws, size_t ws_size,
                              hipStream_t stream) {
    const float* x  = (const float*)d_in[0];
    const int*   ei = (const int*)d_in[1];
    const float* W1 = (const float*)d_in[2];
    const float* b1 = (const float*)d_in[3];
    const float* W2 = (const float*)d_in[4];
    const float* b2 = (const float*)d_in[5];
    const float* W3 = (const float*)d_in[6];
    const float* b3 = (const float*)d_in[7];
    float* out = (float*)d_out;

    const int N = in_sizes[0] / 165;  // 100000
    const int E = in_sizes[1] / 2;    // 3200000
    const int* src = ei;
    const int* dst = ei + E;
    const int nbuk = (N + NPB - 1) >> LOG_NPB;  // 391
    const int NB = (N + NT - 1) / NT;           // 391

    char* p = (char*)d_ws;
    int* gcnt      = (int*)p;      p += (size_t)MAXBUK * 4;
    int* bptr      = (int*)p;      p += (size_t)(MAXBUK + 1) * 4;
    int* cursor    = (int*)p;      p += (size_t)MAXBUK * 4;
    unsigned* ebuf = (unsigned*)p; p += (size_t)E * 4;
    int* esrc      = (int*)p;      p += (size_t)E * 4;
    int* rowptr    = (int*)p;      p += (size_t)(N + 1) * 4;
    float* dinv    = (float*)p;    p += (size_t)N * 4;
    float* hs1     = (float*)p;    p += (size_t)N * 32 * 4;  // blocked [4][N][8]
    float* agg1    = (float*)p;    p += (size_t)N * 32 * 4;  // row-major [N][32]
    float* hs3     = (float*)p;    p += (size_t)N * 2 * 4;
    float* hs2     = hs1;                    // blocked [2][N][8]; hs1 dead then
    float* agg2    = hs1 + (size_t)N * 16;   // row-major [N][16]

    hipMemsetAsync(gcnt, 0, (size_t)MAXBUK * sizeof(int), stream);
    count_kernel<<<(E + EPB_A - 1) / EPB_A, NT, 0, stream>>>(dst, gcnt, E, nbuk);
    scan_kernel<<<1, MAXBUK, 0, stream>>>(gcnt, bptr, cursor, nbuk, E);
    place_kernel<<<(E + EPB_B - 1) / EPB_B, NT, 0, stream>>>(src, dst, cursor, ebuf, E, nbuk);
    sort_kernel<<<nbuk, NT, 0, stream>>>(ebuf, bptr, esrc, rowptr, dinv, N, E);

    const int GB = ((size_t)N * 2 + NT - 1) / NT;  // blocks per gather chunk

    // Layer 1: 165 -> 32, 4 L2-resident chunks
    gemm1_kernel<<<(N + 127) / 128, NT, 0, stream>>>(x, W1, dinv, hs1, N);
    for (int ch = 0; ch < 4; ch++) {
        gather_chunk_kernel<8><<<GB, NT, 0, stream>>>(
            hs1 + (size_t)ch * N * 8, esrc, rowptr, (float4*)agg1 + ch * 2, N);
    }

    // Layer 2: 32 -> 16, 2 L2-resident chunks
    gemm_kernel<32, 16, 2><<<NB, NT, 0, stream>>>(agg1, b1, W2, dinv, hs2, N);
    for (int ch = 0; ch < 2; ch++) {
        gather_chunk_kernel<4><<<GB, NT, 0, stream>>>(
            hs2 + (size_t)ch * N * 8, esrc, rowptr, (float4*)agg2 + ch * 2, N);
    }

    // Layer 3: 16 -> 2, gather + bias + log_softmax fused
    gemm_kernel<16, 2, 0><<<NB, NT, 0, stream>>>(agg2, b2, W3, dinv, hs3, N);
    final_kernel<<<NB, NT, 0, stream>>>(hs3, esrc, rowptr, dinv, b3, out, N);
}

// Round 7
// 512.540 us; speedup vs baseline: 1.0764x; 1.0253x over previous
//
#include <hip/hip_runtime.h>
#include <math.h>

// ---------------------------------------------------------------------------
// GCN 165->32->16->2 + log_softmax, N=100k, E=3.2M.
//
// Round 7:
//  - GEMMs read W/bias via wave-uniform indices -> compiler emits s_load
//    (SMEM pipe, SGPR operand to v_fma). Round 6's gemm1 was LDS-issue bound
//    (4x ds_read_b128 of W per kk = 54 cyc vs 32 cyc FMA). Only the x-tile
//    stays in LDS (bank-clean stride 33). gemm2/3 lose LDS + barrier.
//  - count+scan kernels deleted: fixed-stride bucket regions (BSTRIDE=10240
//    per 256-node bucket; mean fill 8184, sigma 90). place reserves with one
//    atomic per (block,bucket); sort reads cursor[b] as count; per-node
//    rowptr/rowcnt instead of packed CSR.
//  - keep: place (EPT=16) -> per-bucket counting sort -> feature-chunked
//    L2-resident gathers (hs blocked [ch][N][8], 3.2MB/chunk).
// hs = dinv*(in@W); agg[n] = hs[n] + sum_in hs[s];
// next-layer input relu(dinv*agg+b) fused into next GEMM's read.
// ---------------------------------------------------------------------------

constexpr int NT = 256;
constexpr int NPB = 256;       // nodes per bucket (partition)
constexpr int LOG_NPB = 8;
constexpr int MAXBUK = 512;
constexpr int BSTRIDE = 10240; // edge slots per bucket (mean 8184, +22 sigma)
constexpr int EPB_B = 4096;    // edges per block, place pass

__global__ __launch_bounds__(NT) void place_kernel(const int* __restrict__ src,
                                                   const int* __restrict__ dst,
                                                   int* __restrict__ cursor,
                                                   unsigned* __restrict__ ebuf,
                                                   int E, int nbuk) {
    __shared__ int lh[MAXBUK];
    __shared__ int lbase[MAXBUK];
    for (int i = threadIdx.x; i < nbuk; i += NT) lh[i] = 0;
    __syncthreads();
    constexpr int EPT = EPB_B / NT;  // 16
    unsigned pk[EPT];
    unsigned bl[EPT];
    int base = blockIdx.x * EPB_B;
#pragma unroll
    for (int i = 0; i < EPT; i++) {
        int e = base + i * NT + threadIdx.x;
        if (e < E) {
            int s = src[e], d = dst[e];
            int b = d >> LOG_NPB;
            int lp = atomicAdd(&lh[b], 1);
            pk[i] = ((unsigned)(d & (NPB - 1)) << 24) | (unsigned)s;
            bl[i] = ((unsigned)b << 16) | (unsigned)lp;
        } else {
            bl[i] = 0xFFFFFFFFu;
        }
    }
    __syncthreads();
    for (int i = threadIdx.x; i < nbuk; i += NT) {
        int v = lh[i];
        if (v) lbase[i] = atomicAdd(&cursor[i], v);
    }
    __syncthreads();
#pragma unroll
    for (int i = 0; i < EPT; i++) {
        if (bl[i] != 0xFFFFFFFFu) {
            int b = (int)(bl[i] >> 16);
            int pos = lbase[b] + (int)(bl[i] & 0xFFFFu);
            if (pos < BSTRIDE) ebuf[(size_t)b * BSTRIDE + pos] = pk[i];
        }
    }
}

// One block per bucket (256 nodes): in-LDS counting sort of (local<<24)|src
// into node-ordered esrc (bucket-strided); emits rowptr/rowcnt and dinv.
__global__ __launch_bounds__(NT) void sort_kernel(
    const unsigned* __restrict__ ebuf, const int* __restrict__ cursor,
    int* __restrict__ esrc, int* __restrict__ rowptr, int* __restrict__ rowcnt,
    float* __restrict__ dinv, int N) {
    __shared__ int cnt[NPB];
    __shared__ int ofs[NPB];
    __shared__ int cur[NPB];
    int tid = threadIdx.x;
    int b = blockIdx.x;
    cnt[tid] = 0;
    __syncthreads();
    int e0 = b * BSTRIDE;
    int e1 = e0 + min(cursor[b], BSTRIDE);
    for (int i = e0 + tid; i < e1; i += NT)
        atomicAdd(&cnt[ebuf[i] >> 24], 1);
    __syncthreads();
    ofs[tid] = cnt[tid];
    __syncthreads();
    for (int off = 1; off < NPB; off <<= 1) {
        int a = (tid >= off) ? ofs[tid - off] : 0;
        __syncthreads();
        ofs[tid] += a;
        __syncthreads();
    }
    {
        int excl = ofs[tid] - cnt[tid];
        cur[tid] = excl;
        int n = b * NPB + tid;
        if (n < N) {
            rowptr[n] = e0 + excl;
            rowcnt[n] = cnt[tid];
            dinv[n] = rsqrtf((float)cnt[tid] + 1.0f);
        }
    }
    __syncthreads();
    for (int i = e0 + tid; i < e1; i += NT) {
        unsigned p = ebuf[i];
        int l = (int)(p >> 24);
        int pos = atomicAdd(&cur[l], 1);
        esrc[e0 + pos] = (int)(p & 0xFFFFFFu);
    }
}

// Layer 1 GEMM 165->32: thread-per-node; x k-tile staged in LDS (stride 33,
// bank-clean); W read with wave-uniform index -> s_load (SMEM pipe, no
// VALU/LDS cost). Blocked output hs[ch][N][8].
__global__ __launch_bounds__(NT) void gemm1_kernel(
    const float* __restrict__ in, const float* __restrict__ W,
    const float* __restrict__ dinv, float* __restrict__ hs, int N) {
    constexpr int DIN = 165, DOUT = 32, KT = 33;  // 165 = 5*33
    __shared__ float xs[NT * KT];  // 33.8 KB
    int tid = threadIdx.x;
    int n0 = blockIdx.x * NT;
    int n = n0 + tid;
    float acc[DOUT];
#pragma unroll
    for (int d = 0; d < DOUT; d++) acc[d] = 0.f;
    for (int t = 0; t < DIN / KT; t++) {
        int k0 = t * KT;
        __syncthreads();
        for (int f = tid; f < NT * KT; f += NT) {
            int r = f / KT, kk = f - r * KT;
            int nn = n0 + r;
            xs[f] = (nn < N) ? in[(size_t)nn * DIN + k0 + kk] : 0.f;
        }
        __syncthreads();
        for (int kk = 0; kk < KT; kk++) {
            float xv = xs[tid * KT + kk];
#pragma unroll
            for (int d = 0; d < DOUT; d++)
                acc[d] = fmaf(xv, W[(k0 + kk) * DOUT + d], acc[d]);  // uniform -> s_load
        }
    }
    if (n >= N) return;
    float dv = dinv[n];
#pragma unroll
    for (int ch = 0; ch < 4; ch++) {
        float4 h0 = {dv * acc[ch * 8 + 0], dv * acc[ch * 8 + 1],
                     dv * acc[ch * 8 + 2], dv * acc[ch * 8 + 3]};
        float4 h1 = {dv * acc[ch * 8 + 4], dv * acc[ch * 8 + 5],
                     dv * acc[ch * 8 + 6], dv * acc[ch * 8 + 7]};
        float4* hp = (float4*)(hs + ((size_t)ch * N + n) * 8);
        hp[0] = h0;
        hp[1] = h1;
    }
}

// Mid GEMMs: thread-per-node, float4 row loads; W/bias via uniform s_load.
// NCH>0: blocked hs output [NCH][N][8]. NCH=0: row-major float2 (DOUT=2).
template <int DIN, int DOUT, int NCH>
__global__ __launch_bounds__(NT) void gemm_kernel(
    const float* __restrict__ in, const float* __restrict__ bprev,
    const float* __restrict__ W, const float* __restrict__ dinv,
    float* __restrict__ hs, int N) {
    int n = blockIdx.x * NT + threadIdx.x;
    if (n >= N) return;
    float dv = dinv[n];
    float acc[DOUT];
#pragma unroll
    for (int d = 0; d < DOUT; d++) acc[d] = 0.f;
    const float4* row4 = (const float4*)(in + (size_t)n * DIN);
#pragma unroll
    for (int q = 0; q < DIN / 4; q++) {
        float4 v = row4[q];
        float xv[4] = {v.x, v.y, v.z, v.w};
#pragma unroll
        for (int j = 0; j < 4; j++) {
            int k = q * 4 + j;
            float f = fmaxf(fmaf(dv, xv[j], bprev[k]), 0.f);  // bprev[k] uniform
#pragma unroll
            for (int d = 0; d < DOUT; d++)
                acc[d] = fmaf(f, W[k * DOUT + d], acc[d]);    // uniform -> s_load
        }
    }
    if constexpr (NCH > 0) {
#pragma unroll
        for (int ch = 0; ch < NCH; ch++) {
            float4 h0 = {dv * acc[ch * 8 + 0], dv * acc[ch * 8 + 1],
                         dv * acc[ch * 8 + 2], dv * acc[ch * 8 + 3]};
            float4 h1 = {dv * acc[ch * 8 + 4], dv * acc[ch * 8 + 5],
                         dv * acc[ch * 8 + 6], dv * acc[ch * 8 + 7]};
            float4* hp = (float4*)(hs + ((size_t)ch * N + n) * 8);
            hp[0] = h0;
            hp[1] = h1;
        }
    } else {
        float2 h = {dv * acc[0], dv * acc[1]};
        *(float2*)(hs + (size_t)n * 2) = h;
    }
}

// One feature chunk (8 floats/node = 2 float4 lanes). hsC = chunk's [N][8]
// block (3.2MB, L2-resident). aggC row stride OS float4s. Unrolled x4.
template <int OS>
__global__ __launch_bounds__(NT) void gather_chunk_kernel(
    const float* __restrict__ hsC, const int* __restrict__ esrc,
    const int* __restrict__ rowptr, const int* __restrict__ rowcnt,
    float4* __restrict__ aggC, int N) {
    int gid = blockIdx.x * NT + threadIdx.x;
    int n = gid >> 1;
    int c = gid & 1;
    if (n >= N) return;
    int j = rowptr[n];
    int end = j + rowcnt[n];
    const float4* base = (const float4*)hsC;
    float4 acc = base[(size_t)n * 2 + c];  // self-loop message
    for (; j + 4 <= end; j += 4) {
        int s0 = esrc[j], s1 = esrc[j + 1], s2 = esrc[j + 2], s3 = esrc[j + 3];
        float4 v0 = base[(size_t)s0 * 2 + c];
        float4 v1 = base[(size_t)s1 * 2 + c];
        float4 v2 = base[(size_t)s2 * 2 + c];
        float4 v3 = base[(size_t)s3 * 2 + c];
        acc.x += v0.x + v1.x + v2.x + v3.x;
        acc.y += v0.y + v1.y + v2.y + v3.y;
        acc.z += v0.z + v1.z + v2.z + v3.z;
        acc.w += v0.w + v1.w + v2.w + v3.w;
    }
    for (; j < end; j++) {
        float4 v = base[(size_t)esrc[j] * 2 + c];
        acc.x += v.x; acc.y += v.y; acc.z += v.z; acc.w += v.w;
    }
    aggC[(size_t)n * OS + c] = acc;
}

// Layer 3 gather (hs3 0.8MB, L2-resident) + bias + log_softmax.
__global__ __launch_bounds__(NT) void final_kernel(
    const float* __restrict__ hs3, const int* __restrict__ esrc,
    const int* __restrict__ rowptr, const int* __restrict__ rowcnt,
    const float* __restrict__ dinv, const float* __restrict__ b,
    float* __restrict__ out, int N) {
    int n = blockIdx.x * NT + threadIdx.x;
    if (n >= N) return;
    int j = rowptr[n];
    int end = j + rowcnt[n];
    const float2* h2 = (const float2*)hs3;
    float2 acc = h2[n];
    for (; j + 4 <= end; j += 4) {
        float2 v0 = h2[esrc[j]], v1 = h2[esrc[j + 1]];
        float2 v2 = h2[esrc[j + 2]], v3 = h2[esrc[j + 3]];
        acc.x += v0.x + v1.x + v2.x + v3.x;
        acc.y += v0.y + v1.y + v2.y + v3.y;
    }
    for (; j < end; j++) {
        float2 v = h2[esrc[j]];
        acc.x += v.x; acc.y += v.y;
    }
    float dv = dinv[n];
    float z0 = fmaf(dv, acc.x, b[0]);
    float z1 = fmaf(dv, acc.y, b[1]);
    float m = fmaxf(z0, z1);
    float lse = m + logf(expf(z0 - m) + expf(z1 - m));
    out[(size_t)n * 2 + 0] = z0 - lse;
    out[(size_t)n * 2 + 1] = z1 - lse;
}

extern "C" void kernel_launch(void* const* d_in, const int* in_sizes, int n_in,
                              void* d_out, int out_size, void* d_ws, size_t ws_size,
                              hipStream_t stream) {
    const float* x  = (const float*)d_in[0];
    const int*   ei = (const int*)d_in[1];
    const float* W1 = (const float*)d_in[2];
    const float* b1 = (const float*)d_in[3];
    const float* W2 = (const float*)d_in[4];
    const float* b2 = (const float*)d_in[5];
    const float* W3 = (const float*)d_in[6];
    const float* b3 = (const float*)d_in[7];
    float* out = (float*)d_out;

    const int N = in_sizes[0] / 165;  // 100000
    const int E = in_sizes[1] / 2;    // 3200000
    const int* src = ei;
    const int* dst = ei + E;
    const int nbuk = (N + NPB - 1) >> LOG_NPB;  // 391
    const int NB = (N + NT - 1) / NT;           // 391

    char* p = (char*)d_ws;
    int* cursor    = (int*)p;      p += (size_t)MAXBUK * 4;
    unsigned* ebuf = (unsigned*)p; p += (size_t)nbuk * BSTRIDE * 4;
    int* esrc      = (int*)p;      p += (size_t)nbuk * BSTRIDE * 4;
    int* rowptr    = (int*)p;      p += (size_t)N * 4;
    int* rowcnt    = (int*)p;      p += (size_t)N * 4;
    float* dinv    = (float*)p;    p += (size_t)N * 4;
    float* hs1     = (float*)p;    p += (size_t)N * 32 * 4;  // blocked [4][N][8]
    float* agg1    = (float*)p;    p += (size_t)N * 32 * 4;  // row-major [N][32]
    float* hs3     = (float*)p;    p += (size_t)N * 2 * 4;
    float* hs2     = hs1;                    // blocked [2][N][8]; hs1 dead then
    float* agg2    = hs1 + (size_t)N * 16;   // row-major [N][16]

    hipMemsetAsync(cursor, 0, (size_t)MAXBUK * sizeof(int), stream);
    place_kernel<<<(E + EPB_B - 1) / EPB_B, NT, 0, stream>>>(src, dst, cursor, ebuf, E, nbuk);
    sort_kernel<<<nbuk, NT, 0, stream>>>(ebuf, cursor, esrc, rowptr, rowcnt, dinv, N);

    const int GB = ((size_t)N * 2 + NT - 1) / NT;  // blocks per gather chunk

    // Layer 1: 165 -> 32, 4 L2-resident chunks
    gemm1_kernel<<<NB, NT, 0, stream>>>(x, W1, dinv, hs1, N);
    for (int ch = 0; ch < 4; ch++) {
        gather_chunk_kernel<8><<<GB, NT, 0, stream>>>(
            hs1 + (size_t)ch * N * 8, esrc, rowptr, rowcnt, (float4*)agg1 + ch * 2, N);
    }

    // Layer 2: 32 -> 16, 2 L2-resident chunks
    gemm_kernel<32, 16, 2><<<NB, NT, 0, stream>>>(agg1, b1, W2, dinv, hs2, N);
    for (int ch = 0; ch < 2; ch++) {
        gather_chunk_kernel<4><<<GB, NT, 0, stream>>>(
            hs2 + (size_t)ch * N * 8, esrc, rowptr, rowcnt, (float4*)agg2 + ch * 2, N);
    }

    // Layer 3: 16 -> 2, gather + bias + log_softmax fused
    gemm_kernel<16, 2, 0><<<NB, NT, 0, stream>>>(agg2, b2, W3, dinv, hs3, N);
    final_kernel<<<NB, NT, 0, stream>>>(hs3, esrc, rowptr, rowcnt, dinv, b3, out, N);
}

// Round 8
// 442.228 us; speedup vs baseline: 1.2475x; 1.1590x over previous
//
#include <hip/hip_runtime.h>
#include <math.h>

// ---------------------------------------------------------------------------
// GCN 165->32->16->2 + log_softmax, N=100k, E=3.2M.
//
// Round 8:
//  - gemm1 v5: 128-thr blocks (782 blocks, 2x grid vs r7), x k-tile in LDS
//    (16.9KB), W double-buffered in wA/wB uniform register arrays with
//    prefetch-before-use (r7's per-kk s_load+waitcnt serial chain was the
//    125us; r6's LDS W reads were the 76us).
//  - layer-1 messages in bf16: hs1 blocked [2][N][16] bf16 (RNE). Halves the
//    dominant gather traffic (410->205MB) and chunk L2 footprint. Layers 2/3
//    stay f32.
//  - keep: fixed-stride bucket place -> per-bucket counting sort ->
//    register-accumulating chunked gathers; relu(dinv*agg+b) fused into the
//    next GEMM's read.
// ---------------------------------------------------------------------------

constexpr int NT = 256;
constexpr int NPB = 256;       // nodes per bucket (partition)
constexpr int LOG_NPB = 8;
constexpr int MAXBUK = 512;
constexpr int BSTRIDE = 10240; // edge slots per bucket (mean 8184)
constexpr int EPB_B = 4096;    // edges per block, place pass

__device__ inline unsigned short f2bf(float f) {  // RNE f32 -> bf16
    unsigned u = *(unsigned*)&f;
    u += 0x7fffu + ((u >> 16) & 1u);
    return (unsigned short)(u >> 16);
}
__device__ inline unsigned packbf(float a, float b) {
    return (unsigned)f2bf(a) | ((unsigned)f2bf(b) << 16);
}

__global__ __launch_bounds__(NT) void place_kernel(const int* __restrict__ src,
                                                   const int* __restrict__ dst,
                                                   int* __restrict__ cursor,
                                                   unsigned* __restrict__ ebuf,
                                                   int E, int nbuk) {
    __shared__ int lh[MAXBUK];
    __shared__ int lbase[MAXBUK];
    for (int i = threadIdx.x; i < nbuk; i += NT) lh[i] = 0;
    __syncthreads();
    constexpr int EPT = EPB_B / NT;  // 16
    unsigned pk[EPT];
    unsigned bl[EPT];
    int base = blockIdx.x * EPB_B;
#pragma unroll
    for (int i = 0; i < EPT; i++) {
        int e = base + i * NT + threadIdx.x;
        if (e < E) {
            int s = src[e], d = dst[e];
            int b = d >> LOG_NPB;
            int lp = atomicAdd(&lh[b], 1);
            pk[i] = ((unsigned)(d & (NPB - 1)) << 24) | (unsigned)s;
            bl[i] = ((unsigned)b << 16) | (unsigned)lp;
        } else {
            bl[i] = 0xFFFFFFFFu;
        }
    }
    __syncthreads();
    for (int i = threadIdx.x; i < nbuk; i += NT) {
        int v = lh[i];
        if (v) lbase[i] = atomicAdd(&cursor[i], v);
    }
    __syncthreads();
#pragma unroll
    for (int i = 0; i < EPT; i++) {
        if (bl[i] != 0xFFFFFFFFu) {
            int b = (int)(bl[i] >> 16);
            int pos = lbase[b] + (int)(bl[i] & 0xFFFFu);
            if (pos < BSTRIDE) ebuf[(size_t)b * BSTRIDE + pos] = pk[i];
        }
    }
}

// One block per bucket (256 nodes): in-LDS counting sort of (local<<24)|src
// into node-ordered esrc (bucket-strided); emits rowptr/rowcnt and dinv.
__global__ __launch_bounds__(NT) void sort_kernel(
    const unsigned* __restrict__ ebuf, const int* __restrict__ cursor,
    int* __restrict__ esrc, int* __restrict__ rowptr, int* __restrict__ rowcnt,
    float* __restrict__ dinv, int N) {
    __shared__ int cnt[NPB];
    __shared__ int ofs[NPB];
    __shared__ int cur[NPB];
    int tid = threadIdx.x;
    int b = blockIdx.x;
    cnt[tid] = 0;
    __syncthreads();
    int e0 = b * BSTRIDE;
    int e1 = e0 + min(cursor[b], BSTRIDE);
    for (int i = e0 + tid; i < e1; i += NT)
        atomicAdd(&cnt[ebuf[i] >> 24], 1);
    __syncthreads();
    ofs[tid] = cnt[tid];
    __syncthreads();
    for (int off = 1; off < NPB; off <<= 1) {
        int a = (tid >= off) ? ofs[tid - off] : 0;
        __syncthreads();
        ofs[tid] += a;
        __syncthreads();
    }
    {
        int excl = ofs[tid] - cnt[tid];
        cur[tid] = excl;
        int n = b * NPB + tid;
        if (n < N) {
            rowptr[n] = e0 + excl;
            rowcnt[n] = cnt[tid];
            dinv[n] = rsqrtf((float)cnt[tid] + 1.0f);
        }
    }
    __syncthreads();
    for (int i = e0 + tid; i < e1; i += NT) {
        unsigned p = ebuf[i];
        int l = (int)(p >> 24);
        int pos = atomicAdd(&cur[l], 1);
        esrc[e0 + pos] = (int)(p & 0xFFFFFFu);
    }
}

// Layer 1 GEMM 165->32: 128-thr blocks, thread-per-node; x k-tile in LDS
// (stride 33, bank-clean); W in uniform double-buffered register arrays
// (wA/wB), prefetch issued before the dependent FMA burst. Output: bf16
// blocked hs[ch][N][16], ch=0..1 (8 packed uints per chunk per node).
__global__ __launch_bounds__(128) void gemm1_kernel(
    const float* __restrict__ in, const float* __restrict__ W,
    const float* __restrict__ dinv, uint4* __restrict__ hs, int N) {
    constexpr int DIN = 165, DOUT = 32, KT = 33, BN = 128;  // 165 = 5*33
    __shared__ float xs[BN * KT];  // 16.9 KB
    int tid = threadIdx.x;
    int n0 = blockIdx.x * BN;
    int n = n0 + tid;
    float acc[DOUT];
#pragma unroll
    for (int d = 0; d < DOUT; d++) acc[d] = 0.f;
    float wA[DOUT], wB[DOUT];
#pragma unroll
    for (int d = 0; d < DOUT; d++) wA[d] = W[d];  // k = 0
    for (int t = 0; t < DIN / KT; t++) {
        int k0 = t * KT;
        __syncthreads();
        for (int f = tid; f < BN * KT; f += BN) {
            int r = f / KT, kk = f - r * KT;
            int nn = n0 + r;
            xs[f] = (nn < N) ? in[(size_t)nn * DIN + k0 + kk] : 0.f;
        }
        __syncthreads();
        for (int kk = 0; kk + 1 < KT; kk += 2) {
            int k = k0 + kk;
            // prefetch k+1 into wB, then consume wA
#pragma unroll
            for (int d = 0; d < DOUT; d++) wB[d] = W[(k + 1) * DOUT + d];
            float xv = xs[tid * KT + kk];
#pragma unroll
            for (int d = 0; d < DOUT; d++) acc[d] = fmaf(xv, wA[d], acc[d]);
            // prefetch k+2 into wA, then consume wB
#pragma unroll
            for (int d = 0; d < DOUT; d++) wA[d] = W[(k + 2) * DOUT + d];
            float xv2 = xs[tid * KT + kk + 1];
#pragma unroll
            for (int d = 0; d < DOUT; d++) acc[d] = fmaf(xv2, wB[d], acc[d]);
        }
        {   // kk = 32 tail, uses wA (holds k0+32); then prefetch next tile
            float xv = xs[tid * KT + KT - 1];
#pragma unroll
            for (int d = 0; d < DOUT; d++) acc[d] = fmaf(xv, wA[d], acc[d]);
            int kn = (k0 + KT < DIN) ? (k0 + KT) : 0;
#pragma unroll
            for (int d = 0; d < DOUT; d++) wA[d] = W[kn * DOUT + d];
        }
    }
    if (n >= N) return;
    float dv = dinv[n];
#pragma unroll
    for (int ch = 0; ch < 2; ch++) {
        unsigned u[8];
#pragma unroll
        for (int i = 0; i < 8; i++)
            u[i] = packbf(dv * acc[ch * 16 + 2 * i], dv * acc[ch * 16 + 2 * i + 1]);
        hs[((size_t)ch * N + n) * 2 + 0] = make_uint4(u[0], u[1], u[2], u[3]);
        hs[((size_t)ch * N + n) * 2 + 1] = make_uint4(u[4], u[5], u[6], u[7]);
    }
}

// Mid GEMMs: thread-per-node, float4 row loads; W/bias via uniform s_load.
// NCH>0: blocked hs output [NCH][N][8] f32. NCH=0: row-major float2 (DOUT=2).
template <int DIN, int DOUT, int NCH>
__global__ __launch_bounds__(NT) void gemm_kernel(
    const float* __restrict__ in, const float* __restrict__ bprev,
    const float* __restrict__ W, const float* __restrict__ dinv,
    float* __restrict__ hs, int N) {
    int n = blockIdx.x * NT + threadIdx.x;
    if (n >= N) return;
    float dv = dinv[n];
    float acc[DOUT];
#pragma unroll
    for (int d = 0; d < DOUT; d++) acc[d] = 0.f;
    const float4* row4 = (const float4*)(in + (size_t)n * DIN);
#pragma unroll
    for (int q = 0; q < DIN / 4; q++) {
        float4 v = row4[q];
        float xv[4] = {v.x, v.y, v.z, v.w};
#pragma unroll
        for (int j = 0; j < 4; j++) {
            int k = q * 4 + j;
            float f = fmaxf(fmaf(dv, xv[j], bprev[k]), 0.f);
#pragma unroll
            for (int d = 0; d < DOUT; d++)
                acc[d] = fmaf(f, W[k * DOUT + d], acc[d]);
        }
    }
    if constexpr (NCH > 0) {
#pragma unroll
        for (int ch = 0; ch < NCH; ch++) {
            float4 h0 = {dv * acc[ch * 8 + 0], dv * acc[ch * 8 + 1],
                         dv * acc[ch * 8 + 2], dv * acc[ch * 8 + 3]};
            float4 h1 = {dv * acc[ch * 8 + 4], dv * acc[ch * 8 + 5],
                         dv * acc[ch * 8 + 6], dv * acc[ch * 8 + 7]};
            float4* hp = (float4*)(hs + ((size_t)ch * N + n) * 8);
            hp[0] = h0;
            hp[1] = h1;
        }
    } else {
        float2 h = {dv * acc[0], dv * acc[1]};
        *(float2*)(hs + (size_t)n * 2) = h;
    }
}

// Layer-1 gather, bf16 messages. One chunk = 16 features = 32B bf16/node =
// 2 uint4; 2 lanes/node, each lane one uint4 (8 features). Unrolled x4.
__global__ __launch_bounds__(NT) void gather1_kernel(
    const uint4* __restrict__ hsC, const int* __restrict__ esrc,
    const int* __restrict__ rowptr, const int* __restrict__ rowcnt,
    float* __restrict__ agg, int ch, int N) {
    int gid = blockIdx.x * NT + threadIdx.x;
    int n = gid >> 1;
    int c = gid & 1;
    if (n >= N) return;
    int j = rowptr[n];
    int end = j + rowcnt[n];
    float a[8];
    {
        uint4 v = hsC[(size_t)n * 2 + c];  // self-loop message
        const unsigned* u = (const unsigned*)&v;
#pragma unroll
        for (int q = 0; q < 4; q++) {
            unsigned lo = u[q] << 16, hi = u[q] & 0xffff0000u;
            a[2 * q] = *(float*)&lo;
            a[2 * q + 1] = *(float*)&hi;
        }
    }
    for (; j + 4 <= end; j += 4) {
        uint4 v0 = hsC[(size_t)esrc[j] * 2 + c];
        uint4 v1 = hsC[(size_t)esrc[j + 1] * 2 + c];
        uint4 v2 = hsC[(size_t)esrc[j + 2] * 2 + c];
        uint4 v3 = hsC[(size_t)esrc[j + 3] * 2 + c];
        const uint4 vv[4] = {v0, v1, v2, v3};
#pragma unroll
        for (int m = 0; m < 4; m++) {
            const unsigned* u = (const unsigned*)&vv[m];
#pragma unroll
            for (int q = 0; q < 4; q++) {
                unsigned lo = u[q] << 16, hi = u[q] & 0xffff0000u;
                a[2 * q] += *(float*)&lo;
                a[2 * q + 1] += *(float*)&hi;
            }
        }
    }
    for (; j < end; j++) {
        uint4 v = hsC[(size_t)esrc[j] * 2 + c];
        const unsigned* u = (const unsigned*)&v;
#pragma unroll
        for (int q = 0; q < 4; q++) {
            unsigned lo = u[q] << 16, hi = u[q] & 0xffff0000u;
            a[2 * q] += *(float*)&lo;
            a[2 * q + 1] += *(float*)&hi;
        }
    }
    // agg row-major [N][32]; this lane covers features ch*16+c*8 .. +8
    float4* ap = (float4*)agg + (size_t)n * 8 + ch * 4 + c * 2;
    ap[0] = make_float4(a[0], a[1], a[2], a[3]);
    ap[1] = make_float4(a[4], a[5], a[6], a[7]);
}

// f32 chunk gather (8 floats/node = 2 float4 lanes). aggC row stride OS
// float4s. Unrolled x4.
template <int OS>
__global__ __launch_bounds__(NT) void gather_chunk_kernel(
    const float* __restrict__ hsC, const int* __restrict__ esrc,
    const int* __restrict__ rowptr, const int* __restrict__ rowcnt,
    float4* __restrict__ aggC, int N) {
    int gid = blockIdx.x * NT + threadIdx.x;
    int n = gid >> 1;
    int c = gid & 1;
    if (n >= N) return;
    int j = rowptr[n];
    int end = j + rowcnt[n];
    const float4* base = (const float4*)hsC;
    float4 acc = base[(size_t)n * 2 + c];  // self-loop message
    for (; j + 4 <= end; j += 4) {
        int s0 = esrc[j], s1 = esrc[j + 1], s2 = esrc[j + 2], s3 = esrc[j + 3];
        float4 v0 = base[(size_t)s0 * 2 + c];
        float4 v1 = base[(size_t)s1 * 2 + c];
        float4 v2 = base[(size_t)s2 * 2 + c];
        float4 v3 = base[(size_t)s3 * 2 + c];
        acc.x += v0.x + v1.x + v2.x + v3.x;
        acc.y += v0.y + v1.y + v2.y + v3.y;
        acc.z += v0.z + v1.z + v2.z + v3.z;
        acc.w += v0.w + v1.w + v2.w + v3.w;
    }
    for (; j < end; j++) {
        float4 v = base[(size_t)esrc[j] * 2 + c];
        acc.x += v.x; acc.y += v.y; acc.z += v.z; acc.w += v.w;
    }
    aggC[(size_t)n * OS + c] = acc;
}

// Layer 3 gather (hs3 0.8MB) + bias + log_softmax.
__global__ __launch_bounds__(NT) void final_kernel(
    const float* __restrict__ hs3, const int* __restrict__ esrc,
    const int* __restrict__ rowptr, const int* __restrict__ rowcnt,
    const float* __restrict__ dinv, const float* __restrict__ b,
    float* __restrict__ out, int N) {
    int n = blockIdx.x * NT + threadIdx.x;
    if (n >= N) return;
    int j = rowptr[n];
    int end = j + rowcnt[n];
    const float2* h2 = (const float2*)hs3;
    float2 acc = h2[n];
    for (; j + 4 <= end; j += 4) {
        float2 v0 = h2[esrc[j]], v1 = h2[esrc[j + 1]];
        float2 v2 = h2[esrc[j + 2]], v3 = h2[esrc[j + 3]];
        acc.x += v0.x + v1.x + v2.x + v3.x;
        acc.y += v0.y + v1.y + v2.y + v3.y;
    }
    for (; j < end; j++) {
        float2 v = h2[esrc[j]];
        acc.x += v.x; acc.y += v.y;
    }
    float dv = dinv[n];
    float z0 = fmaf(dv, acc.x, b[0]);
    float z1 = fmaf(dv, acc.y, b[1]);
    float m = fmaxf(z0, z1);
    float lse = m + logf(expf(z0 - m) + expf(z1 - m));
    out[(size_t)n * 2 + 0] = z0 - lse;
    out[(size_t)n * 2 + 1] = z1 - lse;
}

extern "C" void kernel_launch(void* const* d_in, const int* in_sizes, int n_in,
                              void* d_out, int out_size, void* d_ws, size_t ws_size,
                              hipStream_t stream) {
    const float* x  = (const float*)d_in[0];
    const int*   ei = (const int*)d_in[1];
    const float* W1 = (const float*)d_in[2];
    const float* b1 = (const float*)d_in[3];
    const float* W2 = (const float*)d_in[4];
    const float* b2 = (const float*)d_in[5];
    const float* W3 = (const float*)d_in[6];
    const float* b3 = (const float*)d_in[7];
    float* out = (float*)d_out;

    const int N = in_sizes[0] / 165;  // 100000
    const int E = in_sizes[1] / 2;    // 3200000
    const int* src = ei;
    const int* dst = ei + E;
    const int nbuk = (N + NPB - 1) >> LOG_NPB;  // 391
    const int NB = (N + NT - 1) / NT;           // 391

    char* p = (char*)d_ws;
    int* cursor    = (int*)p;      p += (size_t)MAXBUK * 4;
    unsigned* ebuf = (unsigned*)p; p += (size_t)nbuk * BSTRIDE * 4;
    int* esrc      = (int*)p;      p += (size_t)nbuk * BSTRIDE * 4;
    int* rowptr    = (int*)p;      p += (size_t)N * 4;
    int* rowcnt    = (int*)p;      p += (size_t)N * 4;
    float* dinv    = (float*)p;    p += (size_t)N * 4;
    uint4* hs1b    = (uint4*)p;    p += (size_t)N * 16 * 4;  // bf16 [2][N][16]
    float* agg1    = (float*)p;    p += (size_t)N * 32 * 4;  // f32 [N][32]
    float* hs2     = (float*)p;    p += (size_t)N * 16 * 4;  // f32 [2][N][8]
    float* hs3     = (float*)p;    p += (size_t)N * 2 * 4;
    float* agg2    = (float*)hs1b;  // hs1b dead after gather1; f32 [N][16]

    hipMemsetAsync(cursor, 0, (size_t)MAXBUK * sizeof(int), stream);
    place_kernel<<<(E + EPB_B - 1) / EPB_B, NT, 0, stream>>>(src, dst, cursor, ebuf, E, nbuk);
    sort_kernel<<<nbuk, NT, 0, stream>>>(ebuf, cursor, esrc, rowptr, rowcnt, dinv, N);

    const int GB = ((size_t)N * 2 + NT - 1) / NT;  // blocks per gather chunk

    // Layer 1: 165 -> 32, bf16 messages, 2 chunks of 16 features
    gemm1_kernel<<<(N + 127) / 128, 128, 0, stream>>>(x, W1, dinv, hs1b, N);
    for (int ch = 0; ch < 2; ch++) {
        gather1_kernel<<<GB, NT, 0, stream>>>(
            hs1b + (size_t)ch * N * 2, esrc, rowptr, rowcnt, agg1, ch, N);
    }

    // Layer 2: 32 -> 16, f32, 2 chunks of 8 features
    gemm_kernel<32, 16, 2><<<NB, NT, 0, stream>>>(agg1, b1, W2, dinv, hs2, N);
    for (int ch = 0; ch < 2; ch++) {
        gather_chunk_kernel<4><<<GB, NT, 0, stream>>>(
            hs2 + (size_t)ch * N * 8, esrc, rowptr, rowcnt, (float4*)agg2 + ch * 2, N);
    }

    // Layer 3: 16 -> 2, gather + bias + log_softmax fused
    gemm_kernel<16, 2, 0><<<NB, NT, 0, stream>>>(agg2, b2, W3, dinv, hs3, N);
    final_kernel<<<NB, NT, 0, stream>>>(hs3, esrc, rowptr, rowcnt, dinv, b3, out, N);
}

// Round 9
// 334.199 us; speedup vs baseline: 1.6508x; 1.3232x over previous
//
#include <hip/hip_runtime.h>
#include <math.h>

// ---------------------------------------------------------------------------
// GCN 165->32->16->2 + log_softmax, N=100k, E=3.2M.
//
// Round 9:
//  - gemm1 via MFMA 16x16x32 bf16. r5-r8 all died on W-operand bandwidth
//    (VALU needs 128 W-vals/cyc/CU; LDS supplies ~21, SMEM less). MFMA holds
//    W in B-fragments (register operands): one wave per 16-node tile, K
//    padded to 192 (6 chunks), 2 B-frags for 32 outputs, C transposed via
//    per-wave LDS tile (stride 36, bank-clean), bf16-packed output.
//  - layer-2 messages bf16 [N][16] (32B/node): halves gather-2 traffic,
//    one dispatch instead of two (same gather1 kernel, stride param).
//  - keep: fixed-stride bucket place -> per-bucket counting sort -> bf16
//    chunked gathers; relu(dinv*agg+b) fused into next GEMM's read.
// ---------------------------------------------------------------------------

constexpr int NT = 256;
constexpr int NPB = 256;       // nodes per bucket (partition)
constexpr int LOG_NPB = 8;
constexpr int MAXBUK = 512;
constexpr int BSTRIDE = 10240; // edge slots per bucket (mean 8184)
constexpr int EPB_B = 4096;    // edges per block, place pass

typedef __attribute__((ext_vector_type(8))) short bf16x8;
typedef __attribute__((ext_vector_type(4))) float f32x4;

__device__ inline unsigned short f2bf(float f) {  // RNE f32 -> bf16
    unsigned u = *(unsigned*)&f;
    u += 0x7fffu + ((u >> 16) & 1u);
    return (unsigned short)(u >> 16);
}
__device__ inline unsigned packbf(float a, float b) {
    return (unsigned)f2bf(a) | ((unsigned)f2bf(b) << 16);
}

__global__ __launch_bounds__(NT) void place_kernel(const int* __restrict__ src,
                                                   const int* __restrict__ dst,
                                                   int* __restrict__ cursor,
                                                   unsigned* __restrict__ ebuf,
                                                   int E, int nbuk) {
    __shared__ int lh[MAXBUK];
    __shared__ int lbase[MAXBUK];
    for (int i = threadIdx.x; i < nbuk; i += NT) lh[i] = 0;
    __syncthreads();
    constexpr int EPT = EPB_B / NT;  // 16
    unsigned pk[EPT];
    unsigned bl[EPT];
    int base = blockIdx.x * EPB_B;
#pragma unroll
    for (int i = 0; i < EPT; i++) {
        int e = base + i * NT + threadIdx.x;
        if (e < E) {
            int s = src[e], d = dst[e];
            int b = d >> LOG_NPB;
            int lp = atomicAdd(&lh[b], 1);
            pk[i] = ((unsigned)(d & (NPB - 1)) << 24) | (unsigned)s;
            bl[i] = ((unsigned)b << 16) | (unsigned)lp;
        } else {
            bl[i] = 0xFFFFFFFFu;
        }
    }
    __syncthreads();
    for (int i = threadIdx.x; i < nbuk; i += NT) {
        int v = lh[i];
        if (v) lbase[i] = atomicAdd(&cursor[i], v);
    }
    __syncthreads();
#pragma unroll
    for (int i = 0; i < EPT; i++) {
        if (bl[i] != 0xFFFFFFFFu) {
            int b = (int)(bl[i] >> 16);
            int pos = lbase[b] + (int)(bl[i] & 0xFFFFu);
            if (pos < BSTRIDE) ebuf[(size_t)b * BSTRIDE + pos] = pk[i];
        }
    }
}

// One block per bucket (256 nodes): in-LDS counting sort of (local<<24)|src
// into node-ordered esrc (bucket-strided); emits rowptr/rowcnt and dinv.
__global__ __launch_bounds__(NT) void sort_kernel(
    const unsigned* __restrict__ ebuf, const int* __restrict__ cursor,
    int* __restrict__ esrc, int* __restrict__ rowptr, int* __restrict__ rowcnt,
    float* __restrict__ dinv, int N) {
    __shared__ int cnt[NPB];
    __shared__ int ofs[NPB];
    __shared__ int cur[NPB];
    int tid = threadIdx.x;
    int b = blockIdx.x;
    cnt[tid] = 0;
    __syncthreads();
    int e0 = b * BSTRIDE;
    int e1 = e0 + min(cursor[b], BSTRIDE);
    for (int i = e0 + tid; i < e1; i += NT)
        atomicAdd(&cnt[ebuf[i] >> 24], 1);
    __syncthreads();
    ofs[tid] = cnt[tid];
    __syncthreads();
    for (int off = 1; off < NPB; off <<= 1) {
        int a = (tid >= off) ? ofs[tid - off] : 0;
        __syncthreads();
        ofs[tid] += a;
        __syncthreads();
    }
    {
        int excl = ofs[tid] - cnt[tid];
        cur[tid] = excl;
        int n = b * NPB + tid;
        if (n < N) {
            rowptr[n] = e0 + excl;
            rowcnt[n] = cnt[tid];
            dinv[n] = rsqrtf((float)cnt[tid] + 1.0f);
        }
    }
    __syncthreads();
    for (int i = e0 + tid; i < e1; i += NT) {
        unsigned p = ebuf[i];
        int l = (int)(p >> 24);
        int pos = atomicAdd(&cur[l], 1);
        esrc[e0 + pos] = (int)(p & 0xFFFFFFu);
    }
}

// Layer 1 GEMM 165->32 via MFMA 16x16x32 bf16. One wave per 16-node tile.
// A frag: x[n0 + (lane&15)][k0 + (lane>>4)*8 + j], j=0..7 (bf16-converted).
// B frag: W[k0 + (lane>>4)*8 + j][col], col = lane&15 (+16 for 2nd frag).
// C/D:    col = lane&15, row = (lane>>4)*4 + reg.
// Epilogue: C -> per-wave LDS tile (stride 36, 16B-aligned rows) -> dv scale
// -> bf16 pack -> blocked hs[ch][N][16] bf16 (uint4 pairs), ch = 0..1.
__global__ __launch_bounds__(NT) void gemm1_mfma(
    const float* __restrict__ in, const float* __restrict__ W,
    const float* __restrict__ dinv, uint4* __restrict__ hs, int Ntot) {
    constexpr int DIN = 165, DOUT = 32;
    __shared__ float tile[4][16][36];  // 9.2 KB, per-wave slices
    int lane = threadIdx.x & 63;
    int wv = threadIdx.x >> 6;
    int t = blockIdx.x * 4 + wv;
    int ntiles = (Ntot + 15) >> 4;
    if (t >= ntiles) return;
    int n0 = t << 4;
    int mrow = lane & 15;
    int quad = lane >> 4;
    int arow = n0 + mrow;
    if (arow >= Ntot) arow = Ntot - 1;  // clamp (read-only safety)
    const float* xrow = in + (size_t)arow * DIN;
    f32x4 acc0 = {0.f, 0.f, 0.f, 0.f};
    f32x4 acc1 = {0.f, 0.f, 0.f, 0.f};
#pragma unroll
    for (int c = 0; c < 6; c++) {
        int kb = c * 32 + quad * 8;
        union { bf16x8 v; unsigned short u[8]; } A, B0, B1;
#pragma unroll
        for (int j = 0; j < 8; j++) {
            int k = kb + j;
            float xv = (k < DIN) ? xrow[k] : 0.f;
            float w0 = (k < DIN) ? W[k * DOUT + mrow] : 0.f;
            float w1 = (k < DIN) ? W[k * DOUT + 16 + mrow] : 0.f;
            A.u[j] = f2bf(xv);
            B0.u[j] = f2bf(w0);
            B1.u[j] = f2bf(w1);
        }
        acc0 = __builtin_amdgcn_mfma_f32_16x16x32_bf16(A.v, B0.v, acc0, 0, 0, 0);
        acc1 = __builtin_amdgcn_mfma_f32_16x16x32_bf16(A.v, B1.v, acc1, 0, 0, 0);
    }
    // C -> LDS (wave-private slice; same-wave DS ops are ordered, no barrier)
#pragma unroll
    for (int r = 0; r < 4; r++) {
        tile[wv][quad * 4 + r][mrow] = acc0[r];
        tile[wv][quad * 4 + r][16 + mrow] = acc1[r];
    }
    // lane -> (node, 8-feature part): 4 lanes per node
    int node = lane >> 2;
    int part = lane & 3;          // features part*8 .. part*8+7
    int n = n0 + node;
    if (n >= Ntot) return;
    float dv = dinv[n];
    float f[8];
#pragma unroll
    for (int i = 0; i < 8; i++) f[i] = tile[wv][node][part * 8 + i];
    unsigned u0 = packbf(dv * f[0], dv * f[1]);
    unsigned u1 = packbf(dv * f[2], dv * f[3]);
    unsigned u2 = packbf(dv * f[4], dv * f[5]);
    unsigned u3 = packbf(dv * f[6], dv * f[7]);
    int ch = part >> 1;           // 16-feature chunk index
    int half = part & 1;          // which uint4 within the chunk
    hs[((size_t)ch * Ntot + n) * 2 + half] = make_uint4(u0, u1, u2, u3);
}

// Mid GEMMs: thread-per-node, float4 row loads; W/bias via uniform s_load.
// OUT==1 (DOUT=16): bf16-packed [N][16] (2 uint4/node). OUT==0 (DOUT=2): f32.
template <int DIN, int DOUT, int OUT>
__global__ __launch_bounds__(NT) void gemm_kernel(
    const float* __restrict__ in, const float* __restrict__ bprev,
    const float* __restrict__ W, const float* __restrict__ dinv,
    void* __restrict__ hs, int N) {
    int n = blockIdx.x * NT + threadIdx.x;
    if (n >= N) return;
    float dv = dinv[n];
    float acc[DOUT];
#pragma unroll
    for (int d = 0; d < DOUT; d++) acc[d] = 0.f;
    const float4* row4 = (const float4*)(in + (size_t)n * DIN);
#pragma unroll
    for (int q = 0; q < DIN / 4; q++) {
        float4 v = row4[q];
        float xv[4] = {v.x, v.y, v.z, v.w};
#pragma unroll
        for (int j = 0; j < 4; j++) {
            int k = q * 4 + j;
            float f = fmaxf(fmaf(dv, xv[j], bprev[k]), 0.f);
#pragma unroll
            for (int d = 0; d < DOUT; d++)
                acc[d] = fmaf(f, W[k * DOUT + d], acc[d]);
        }
    }
    if constexpr (OUT == 1) {
        unsigned u[8];
#pragma unroll
        for (int i = 0; i < 8; i++)
            u[i] = packbf(dv * acc[2 * i], dv * acc[2 * i + 1]);
        uint4* hp = (uint4*)hs + (size_t)n * 2;
        hp[0] = make_uint4(u[0], u[1], u[2], u[3]);
        hp[1] = make_uint4(u[4], u[5], u[6], u[7]);
    } else {
        float2 h = {dv * acc[0], dv * acc[1]};
        *(float2*)((float*)hs + (size_t)n * 2) = h;
    }
}

// bf16 chunk gather: hsC = [N][2]uint4 (16 bf16 feats/node); 2 lanes/node,
// each lane one uint4 (8 feats). Register accumulation, unrolled x4.
// Writes 2 float4 at aggBase[n*strideF4 + baseOfs + c*2].
__global__ __launch_bounds__(NT) void gather1_kernel(
    const uint4* __restrict__ hsC, const int* __restrict__ esrc,
    const int* __restrict__ rowptr, const int* __restrict__ rowcnt,
    float4* __restrict__ aggBase, int strideF4, int baseOfs, int N) {
    int gid = blockIdx.x * NT + threadIdx.x;
    int n = gid >> 1;
    int c = gid & 1;
    if (n >= N) return;
    int j = rowptr[n];
    int end = j + rowcnt[n];
    float a[8];
    {
        uint4 v = hsC[(size_t)n * 2 + c];  // self-loop message
        const unsigned* u = (const unsigned*)&v;
#pragma unroll
        for (int q = 0; q < 4; q++) {
            unsigned lo = u[q] << 16, hi = u[q] & 0xffff0000u;
            a[2 * q] = *(float*)&lo;
            a[2 * q + 1] = *(float*)&hi;
        }
    }
    for (; j + 4 <= end; j += 4) {
        uint4 v0 = hsC[(size_t)esrc[j] * 2 + c];
        uint4 v1 = hsC[(size_t)esrc[j + 1] * 2 + c];
        uint4 v2 = hsC[(size_t)esrc[j + 2] * 2 + c];
        uint4 v3 = hsC[(size_t)esrc[j + 3] * 2 + c];
        const uint4 vv[4] = {v0, v1, v2, v3};
#pragma unroll
        for (int m = 0; m < 4; m++) {
            const unsigned* u = (const unsigned*)&vv[m];
#pragma unroll
            for (int q = 0; q < 4; q++) {
                unsigned lo = u[q] << 16, hi = u[q] & 0xffff0000u;
                a[2 * q] += *(float*)&lo;
                a[2 * q + 1] += *(float*)&hi;
            }
        }
    }
    for (; j < end; j++) {
        uint4 v = hsC[(size_t)esrc[j] * 2 + c];
        const unsigned* u = (const unsigned*)&v;
#pragma unroll
        for (int q = 0; q < 4; q++) {
            unsigned lo = u[q] << 16, hi = u[q] & 0xffff0000u;
            a[2 * q] += *(float*)&lo;
            a[2 * q + 1] += *(float*)&hi;
        }
    }
    float4* ap = aggBase + (size_t)n * strideF4 + baseOfs + c * 2;
    ap[0] = make_float4(a[0], a[1], a[2], a[3]);
    ap[1] = make_float4(a[4], a[5], a[6], a[7]);
}

// Layer 3 gather (hs3 0.8MB) + bias + log_softmax.
__global__ __launch_bounds__(NT) void final_kernel(
    const float* __restrict__ hs3, const int* __restrict__ esrc,
    const int* __restrict__ rowptr, const int* __restrict__ rowcnt,
    const float* __restrict__ dinv, const float* __restrict__ b,
    float* __restrict__ out, int N) {
    int n = blockIdx.x * NT + threadIdx.x;
    if (n >= N) return;
    int j = rowptr[n];
    int end = j + rowcnt[n];
    const float2* h2 = (const float2*)hs3;
    float2 acc = h2[n];
    for (; j + 4 <= end; j += 4) {
        float2 v0 = h2[esrc[j]], v1 = h2[esrc[j + 1]];
        float2 v2 = h2[esrc[j + 2]], v3 = h2[esrc[j + 3]];
        acc.x += v0.x + v1.x + v2.x + v3.x;
        acc.y += v0.y + v1.y + v2.y + v3.y;
    }
    for (; j < end; j++) {
        float2 v = h2[esrc[j]];
        acc.x += v.x; acc.y += v.y;
    }
    float dv = dinv[n];
    float z0 = fmaf(dv, acc.x, b[0]);
    float z1 = fmaf(dv, acc.y, b[1]);
    float m = fmaxf(z0, z1);
    float lse = m + logf(expf(z0 - m) + expf(z1 - m));
    out[(size_t)n * 2 + 0] = z0 - lse;
    out[(size_t)n * 2 + 1] = z1 - lse;
}

extern "C" void kernel_launch(void* const* d_in, const int* in_sizes, int n_in,
                              void* d_out, int out_size, void* d_ws, size_t ws_size,
                              hipStream_t stream) {
    const float* x  = (const float*)d_in[0];
    const int*   ei = (const int*)d_in[1];
    const float* W1 = (const float*)d_in[2];
    const float* b1 = (const float*)d_in[3];
    const float* W2 = (const float*)d_in[4];
    const float* b2 = (const float*)d_in[5];
    const float* W3 = (const float*)d_in[6];
    const float* b3 = (const float*)d_in[7];
    float* out = (float*)d_out;

    const int N = in_sizes[0] / 165;  // 100000
    const int E = in_sizes[1] / 2;    // 3200000
    const int* src = ei;
    const int* dst = ei + E;
    const int nbuk = (N + NPB - 1) >> LOG_NPB;  // 391
    const int NB = (N + NT - 1) / NT;           // 391

    char* p = (char*)d_ws;
    int* cursor    = (int*)p;      p += (size_t)MAXBUK * 4;
    unsigned* ebuf = (unsigned*)p; p += (size_t)nbuk * BSTRIDE * 4;
    int* esrc      = (int*)p;      p += (size_t)nbuk * BSTRIDE * 4;
    int* rowptr    = (int*)p;      p += (size_t)N * 4;
    int* rowcnt    = (int*)p;      p += (size_t)N * 4;
    float* dinv    = (float*)p;    p += (size_t)N * 4;
    uint4* hs1b    = (uint4*)p;    p += (size_t)N * 16 * 4;  // bf16 [2][N][16]
    float* agg1    = (float*)p;    p += (size_t)N * 32 * 4;  // f32 [N][32]
    uint4* hs2b    = (uint4*)p;    p += (size_t)N * 8 * 4;   // bf16 [N][16]
    float* hs3     = (float*)p;    p += (size_t)N * 2 * 4;
    float* agg2    = (float*)hs1b;  // hs1b dead after gather1; f32 [N][16]

    hipMemsetAsync(cursor, 0, (size_t)MAXBUK * sizeof(int), stream);
    place_kernel<<<(E + EPB_B - 1) / EPB_B, NT, 0, stream>>>(src, dst, cursor, ebuf, E, nbuk);
    sort_kernel<<<nbuk, NT, 0, stream>>>(ebuf, cursor, esrc, rowptr, rowcnt, dinv, N);

    const int GB = ((size_t)N * 2 + NT - 1) / NT;  // blocks per gather dispatch

    // Layer 1: 165 -> 32, MFMA, bf16 messages, 2 chunks of 16 features
    gemm1_mfma<<<((N + 15) / 16 + 3) / 4, NT, 0, stream>>>(x, W1, dinv, hs1b, N);
    for (int ch = 0; ch < 2; ch++) {
        gather1_kernel<<<GB, NT, 0, stream>>>(
            hs1b + (size_t)ch * N * 2, esrc, rowptr, rowcnt,
            (float4*)agg1, 8, ch * 4, N);
    }

    // Layer 2: 32 -> 16, bf16 messages, single 16-feature chunk
    gemm_kernel<32, 16, 1><<<NB, NT, 0, stream>>>(agg1, b1, W2, dinv, hs2b, N);
    gather1_kernel<<<GB, NT, 0, stream>>>(
        hs2b, esrc, rowptr, rowcnt, (float4*)agg2, 4, 0, N);

    // Layer 3: 16 -> 2, gather + bias + log_softmax fused
    gemm_kernel<16, 2, 0><<<NB, NT, 0, stream>>>(agg2, b2, W3, dinv, hs3, N);
    final_kernel<<<NB, NT, 0, stream>>>(hs3, esrc, rowptr, rowcnt, dinv, b3, out, N);
}

// Round 10
// 326.591 us; speedup vs baseline: 1.6892x; 1.0233x over previous
//
#include <hip/hip_runtime.h>
#include <math.h>

// ---------------------------------------------------------------------------
// GCN 165->32->16->2 + log_softmax, N=100k, E=3.2M.
//
// Round 10 (r9 + contention fix):
//  - place: 8-way replicated cursor + 8 fixed subregions per bucket
//    (SUB=1280, mean fill 1023, +8sigma). The r9 place (44us) was bound by
//    306k device-scope atomics on 391 hot words (~782 serialized cross-XCD
//    RMWs per word); replicas cut that to ~98 per word.
//  - sort: iterates the 8 packed subregions per bucket; same total reads.
//  - keep: gemm1 MFMA 16x16x32 bf16 (r9 removed gemm1 from top-5), bf16
//    message gathers, fused relu(dinv*agg+b) in next GEMM's read.
// ---------------------------------------------------------------------------

constexpr int NT = 256;
constexpr int NPB = 256;       // nodes per bucket (partition)
constexpr int LOG_NPB = 8;
constexpr int MAXBUK = 512;
constexpr int BSTRIDE = 10240; // edge slots per bucket (mean 8184)
constexpr int NREP = 8;        // cursor replicas / subregions per bucket
constexpr int SUB = BSTRIDE / NREP;  // 1280 slots per subregion
constexpr int EPB_B = 4096;    // edges per block, place pass

typedef __attribute__((ext_vector_type(8))) short bf16x8;
typedef __attribute__((ext_vector_type(4))) float f32x4;

__device__ inline unsigned short f2bf(float f) {  // RNE f32 -> bf16
    unsigned u = *(unsigned*)&f;
    u += 0x7fffu + ((u >> 16) & 1u);
    return (unsigned short)(u >> 16);
}
__device__ inline unsigned packbf(float a, float b) {
    return (unsigned)f2bf(a) | ((unsigned)f2bf(b) << 16);
}

__global__ __launch_bounds__(NT) void place_kernel(const int* __restrict__ src,
                                                   const int* __restrict__ dst,
                                                   int* __restrict__ cursor8,
                                                   unsigned* __restrict__ ebuf,
                                                   int E, int nbuk) {
    __shared__ int lh[MAXBUK];
    __shared__ int lbase[MAXBUK];
    for (int i = threadIdx.x; i < nbuk; i += NT) lh[i] = 0;
    __syncthreads();
    constexpr int EPT = EPB_B / NT;  // 16
    unsigned pk[EPT];
    unsigned bl[EPT];
    int base = blockIdx.x * EPB_B;
    int rep = blockIdx.x & (NREP - 1);
#pragma unroll
    for (int i = 0; i < EPT; i++) {
        int e = base + i * NT + threadIdx.x;
        if (e < E) {
            int s = src[e], d = dst[e];
            int b = d >> LOG_NPB;
            int lp = atomicAdd(&lh[b], 1);
            pk[i] = ((unsigned)(d & (NPB - 1)) << 24) | (unsigned)s;
            bl[i] = ((unsigned)b << 16) | (unsigned)lp;
        } else {
            bl[i] = 0xFFFFFFFFu;
        }
    }
    __syncthreads();
    for (int i = threadIdx.x; i < nbuk; i += NT) {
        int v = lh[i];
        if (v) lbase[i] = atomicAdd(&cursor8[rep * MAXBUK + i], v);
    }
    __syncthreads();
#pragma unroll
    for (int i = 0; i < EPT; i++) {
        if (bl[i] != 0xFFFFFFFFu) {
            int b = (int)(bl[i] >> 16);
            int pos = lbase[b] + (int)(bl[i] & 0xFFFFu);
            if (pos < SUB)
                ebuf[(size_t)b * BSTRIDE + rep * SUB + pos] = pk[i];
        }
    }
}

// One block per bucket (256 nodes): in-LDS counting sort of (local<<24)|src
// from the 8 packed subregions into node-ordered esrc (bucket-strided);
// emits rowptr/rowcnt and dinv. Output range block-exclusive.
__global__ __launch_bounds__(NT) void sort_kernel(
    const unsigned* __restrict__ ebuf, const int* __restrict__ cursor8,
    int* __restrict__ esrc, int* __restrict__ rowptr, int* __restrict__ rowcnt,
    float* __restrict__ dinv, int N) {
    __shared__ int cnt[NPB];
    __shared__ int ofs[NPB];
    __shared__ int cur[NPB];
    int tid = threadIdx.x;
    int b = blockIdx.x;
    cnt[tid] = 0;
    __syncthreads();
#pragma unroll
    for (int r = 0; r < NREP; r++) {
        int e0 = b * BSTRIDE + r * SUB;
        int e1 = e0 + min(cursor8[r * MAXBUK + b], SUB);
        for (int i = e0 + tid; i < e1; i += NT)
            atomicAdd(&cnt[ebuf[i] >> 24], 1);
    }
    __syncthreads();
    ofs[tid] = cnt[tid];
    __syncthreads();
    for (int off = 1; off < NPB; off <<= 1) {
        int a = (tid >= off) ? ofs[tid - off] : 0;
        __syncthreads();
        ofs[tid] += a;
        __syncthreads();
    }
    {
        int excl = ofs[tid] - cnt[tid];
        cur[tid] = excl;
        int n = b * NPB + tid;
        if (n < N) {
            rowptr[n] = b * BSTRIDE + excl;
            rowcnt[n] = cnt[tid];
            dinv[n] = rsqrtf((float)cnt[tid] + 1.0f);
        }
    }
    __syncthreads();
#pragma unroll
    for (int r = 0; r < NREP; r++) {
        int e0 = b * BSTRIDE + r * SUB;
        int e1 = e0 + min(cursor8[r * MAXBUK + b], SUB);
        for (int i = e0 + tid; i < e1; i += NT) {
            unsigned p = ebuf[i];
            int l = (int)(p >> 24);
            int pos = atomicAdd(&cur[l], 1);
            esrc[b * BSTRIDE + pos] = (int)(p & 0xFFFFFFu);
        }
    }
}

// Layer 1 GEMM 165->32 via MFMA 16x16x32 bf16. One wave per 16-node tile.
// A frag: x[n0 + (lane&15)][k0 + (lane>>4)*8 + j]; B frag: W[k][col].
// C/D: col = lane&15, row = (lane>>4)*4 + reg. Epilogue via per-wave LDS
// tile -> dv scale -> bf16 pack -> blocked hs[ch][N][16], ch=0..1.
__global__ __launch_bounds__(NT) void gemm1_mfma(
    const float* __restrict__ in, const float* __restrict__ W,
    const float* __restrict__ dinv, uint4* __restrict__ hs, int Ntot) {
    constexpr int DIN = 165, DOUT = 32;
    __shared__ float tile[4][16][36];  // per-wave slices
    int lane = threadIdx.x & 63;
    int wv = threadIdx.x >> 6;
    int t = blockIdx.x * 4 + wv;
    int ntiles = (Ntot + 15) >> 4;
    if (t >= ntiles) return;
    int n0 = t << 4;
    int mrow = lane & 15;
    int quad = lane >> 4;
    int arow = n0 + mrow;
    if (arow >= Ntot) arow = Ntot - 1;  // clamp (read-only safety)
    const float* xrow = in + (size_t)arow * DIN;
    f32x4 acc0 = {0.f, 0.f, 0.f, 0.f};
    f32x4 acc1 = {0.f, 0.f, 0.f, 0.f};
#pragma unroll
    for (int c = 0; c < 6; c++) {
        int kb = c * 32 + quad * 8;
        union { bf16x8 v; unsigned short u[8]; } A, B0, B1;
#pragma unroll
        for (int j = 0; j < 8; j++) {
            int k = kb + j;
            float xv = (k < DIN) ? xrow[k] : 0.f;
            float w0 = (k < DIN) ? W[k * DOUT + mrow] : 0.f;
            float w1 = (k < DIN) ? W[k * DOUT + 16 + mrow] : 0.f;
            A.u[j] = f2bf(xv);
            B0.u[j] = f2bf(w0);
            B1.u[j] = f2bf(w1);
        }
        acc0 = __builtin_amdgcn_mfma_f32_16x16x32_bf16(A.v, B0.v, acc0, 0, 0, 0);
        acc1 = __builtin_amdgcn_mfma_f32_16x16x32_bf16(A.v, B1.v, acc1, 0, 0, 0);
    }
#pragma unroll
    for (int r = 0; r < 4; r++) {
        tile[wv][quad * 4 + r][mrow] = acc0[r];
        tile[wv][quad * 4 + r][16 + mrow] = acc1[r];
    }
    int node = lane >> 2;
    int part = lane & 3;          // features part*8 .. part*8+7
    int n = n0 + node;
    if (n >= Ntot) return;
    float dv = dinv[n];
    float f[8];
#pragma unroll
    for (int i = 0; i < 8; i++) f[i] = tile[wv][node][part * 8 + i];
    unsigned u0 = packbf(dv * f[0], dv * f[1]);
    unsigned u1 = packbf(dv * f[2], dv * f[3]);
    unsigned u2 = packbf(dv * f[4], dv * f[5]);
    unsigned u3 = packbf(dv * f[6], dv * f[7]);
    int ch = part >> 1;
    int half = part & 1;
    hs[((size_t)ch * Ntot + n) * 2 + half] = make_uint4(u0, u1, u2, u3);
}

// Mid GEMMs: thread-per-node, float4 row loads; W/bias via uniform s_load.
// OUT==1 (DOUT=16): bf16-packed [N][16] (2 uint4/node). OUT==0 (DOUT=2): f32.
template <int DIN, int DOUT, int OUT>
__global__ __launch_bounds__(NT) void gemm_kernel(
    const float* __restrict__ in, const float* __restrict__ bprev,
    const float* __restrict__ W, const float* __restrict__ dinv,
    void* __restrict__ hs, int N) {
    int n = blockIdx.x * NT + threadIdx.x;
    if (n >= N) return;
    float dv = dinv[n];
    float acc[DOUT];
#pragma unroll
    for (int d = 0; d < DOUT; d++) acc[d] = 0.f;
    const float4* row4 = (const float4*)(in + (size_t)n * DIN);
#pragma unroll
    for (int q = 0; q < DIN / 4; q++) {
        float4 v = row4[q];
        float xv[4] = {v.x, v.y, v.z, v.w};
#pragma unroll
        for (int j = 0; j < 4; j++) {
            int k = q * 4 + j;
            float f = fmaxf(fmaf(dv, xv[j], bprev[k]), 0.f);
#pragma unroll
            for (int d = 0; d < DOUT; d++)
                acc[d] = fmaf(f, W[k * DOUT + d], acc[d]);
        }
    }
    if constexpr (OUT == 1) {
        unsigned u[8];
#pragma unroll
        for (int i = 0; i < 8; i++)
            u[i] = packbf(dv * acc[2 * i], dv * acc[2 * i + 1]);
        uint4* hp = (uint4*)hs + (size_t)n * 2;
        hp[0] = make_uint4(u[0], u[1], u[2], u[3]);
        hp[1] = make_uint4(u[4], u[5], u[6], u[7]);
    } else {
        float2 h = {dv * acc[0], dv * acc[1]};
        *(float2*)((float*)hs + (size_t)n * 2) = h;
    }
}

// bf16 chunk gather: hsC = [N][2]uint4 (16 bf16 feats/node); 2 lanes/node,
// each lane one uint4 (8 feats). Register accumulation, unrolled x4.
// Writes 2 float4 at aggBase[n*strideF4 + baseOfs + c*2].
__global__ __launch_bounds__(NT) void gather1_kernel(
    const uint4* __restrict__ hsC, const int* __restrict__ esrc,
    const int* __restrict__ rowptr, const int* __restrict__ rowcnt,
    float4* __restrict__ aggBase, int strideF4, int baseOfs, int N) {
    int gid = blockIdx.x * NT + threadIdx.x;
    int n = gid >> 1;
    int c = gid & 1;
    if (n >= N) return;
    int j = rowptr[n];
    int end = j + rowcnt[n];
    float a[8];
    {
        uint4 v = hsC[(size_t)n * 2 + c];  // self-loop message
        const unsigned* u = (const unsigned*)&v;
#pragma unroll
        for (int q = 0; q < 4; q++) {
            unsigned lo = u[q] << 16, hi = u[q] & 0xffff0000u;
            a[2 * q] = *(float*)&lo;
            a[2 * q + 1] = *(float*)&hi;
        }
    }
    for (; j + 4 <= end; j += 4) {
        uint4 v0 = hsC[(size_t)esrc[j] * 2 + c];
        uint4 v1 = hsC[(size_t)esrc[j + 1] * 2 + c];
        uint4 v2 = hsC[(size_t)esrc[j + 2] * 2 + c];
        uint4 v3 = hsC[(size_t)esrc[j + 3] * 2 + c];
        const uint4 vv[4] = {v0, v1, v2, v3};
#pragma unroll
        for (int m = 0; m < 4; m++) {
            const unsigned* u = (const unsigned*)&vv[m];
#pragma unroll
            for (int q = 0; q < 4; q++) {
                unsigned lo = u[q] << 16, hi = u[q] & 0xffff0000u;
                a[2 * q] += *(float*)&lo;
                a[2 * q + 1] += *(float*)&hi;
            }
        }
    }
    for (; j < end; j++) {
        uint4 v = hsC[(size_t)esrc[j] * 2 + c];
        const unsigned* u = (const unsigned*)&v;
#pragma unroll
        for (int q = 0; q < 4; q++) {
            unsigned lo = u[q] << 16, hi = u[q] & 0xffff0000u;
            a[2 * q] += *(float*)&lo;
            a[2 * q + 1] += *(float*)&hi;
        }
    }
    float4* ap = aggBase + (size_t)n * strideF4 + baseOfs + c * 2;
    ap[0] = make_float4(a[0], a[1], a[2], a[3]);
    ap[1] = make_float4(a[4], a[5], a[6], a[7]);
}

// Layer 3 gather (hs3 0.8MB) + bias + log_softmax.
__global__ __launch_bounds__(NT) void final_kernel(
    const float* __restrict__ hs3, const int* __restrict__ esrc,
    const int* __restrict__ rowptr, const int* __restrict__ rowcnt,
    const float* __restrict__ dinv, const float* __restrict__ b,
    float* __restrict__ out, int N) {
    int n = blockIdx.x * NT + threadIdx.x;
    if (n >= N) return;
    int j = rowptr[n];
    int end = j + rowcnt[n];
    const float2* h2 = (const float2*)hs3;
    float2 acc = h2[n];
    for (; j + 4 <= end; j += 4) {
        float2 v0 = h2[esrc[j]], v1 = h2[esrc[j + 1]];
        float2 v2 = h2[esrc[j + 2]], v3 = h2[esrc[j + 3]];
        acc.x += v0.x + v1.x + v2.x + v3.x;
        acc.y += v0.y + v1.y + v2.y + v3.y;
    }
    for (; j < end; j++) {
        float2 v = h2[esrc[j]];
        acc.x += v.x; acc.y += v.y;
    }
    float dv = dinv[n];
    float z0 = fmaf(dv, acc.x, b[0]);
    float z1 = fmaf(dv, acc.y, b[1]);
    float m = fmaxf(z0, z1);
    float lse = m + logf(expf(z0 - m) + expf(z1 - m));
    out[(size_t)n * 2 + 0] = z0 - lse;
    out[(size_t)n * 2 + 1] = z1 - lse;
}

extern "C" void kernel_launch(void* const* d_in, const int* in_sizes, int n_in,
                              void* d_out, int out_size, void* d_ws, size_t ws_size,
                              hipStream_t stream) {
    const float* x  = (const float*)d_in[0];
    const int*   ei = (const int*)d_in[1];
    const float* W1 = (const float*)d_in[2];
    const float* b1 = (const float*)d_in[3];
    const float* W2 = (const float*)d_in[4];
    const float* b2 = (const float*)d_in[5];
    const float* W3 = (const float*)d_in[6];
    const float* b3 = (const float*)d_in[7];
    float* out = (float*)d_out;

    const int N = in_sizes[0] / 165;  // 100000
    const int E = in_sizes[1] / 2;    // 3200000
    const int* src = ei;
    const int* dst = ei + E;
    const int nbuk = (N + NPB - 1) >> LOG_NPB;  // 391
    const int NB = (N + NT - 1) / NT;           // 391

    char* p = (char*)d_ws;
    int* cursor8   = (int*)p;      p += (size_t)NREP * MAXBUK * 4;
    unsigned* ebuf = (unsigned*)p; p += (size_t)nbuk * BSTRIDE * 4;
    int* esrc      = (int*)p;      p += (size_t)nbuk * BSTRIDE * 4;
    int* rowptr    = (int*)p;      p += (size_t)N * 4;
    int* rowcnt    = (int*)p;      p += (size_t)N * 4;
    float* dinv    = (float*)p;    p += (size_t)N * 4;
    uint4* hs1b    = (uint4*)p;    p += (size_t)N * 16 * 4;  // bf16 [2][N][16]
    float* agg1    = (float*)p;    p += (size_t)N * 32 * 4;  // f32 [N][32]
    uint4* hs2b    = (uint4*)p;    p += (size_t)N * 8 * 4;   // bf16 [N][16]
    float* hs3     = (float*)p;    p += (size_t)N * 2 * 4;
    float* agg2    = (float*)hs1b;  // hs1b dead after gather1; f32 [N][16]

    hipMemsetAsync(cursor8, 0, (size_t)NREP * MAXBUK * sizeof(int), stream);
    place_kernel<<<(E + EPB_B - 1) / EPB_B, NT, 0, stream>>>(src, dst, cursor8, ebuf, E, nbuk);
    sort_kernel<<<nbuk, NT, 0, stream>>>(ebuf, cursor8, esrc, rowptr, rowcnt, dinv, N);

    const int GB = ((size_t)N * 2 + NT - 1) / NT;  // blocks per gather dispatch

    // Layer 1: 165 -> 32, MFMA, bf16 messages, 2 chunks of 16 features
    gemm1_mfma<<<((N + 15) / 16 + 3) / 4, NT, 0, stream>>>(x, W1, dinv, hs1b, N);
    for (int ch = 0; ch < 2; ch++) {
        gather1_kernel<<<GB, NT, 0, stream>>>(
            hs1b + (size_t)ch * N * 2, esrc, rowptr, rowcnt,
            (float4*)agg1, 8, ch * 4, N);
    }

    // Layer 2: 32 -> 16, bf16 messages, single 16-feature chunk
    gemm_kernel<32, 16, 1><<<NB, NT, 0, stream>>>(agg1, b1, W2, dinv, hs2b, N);
    gather1_kernel<<<GB, NT, 0, stream>>>(
        hs2b, esrc, rowptr, rowcnt, (float4*)agg2, 4, 0, N);

    // Layer 3: 16 -> 2, gather + bias + log_softmax fused
    gemm_kernel<16, 2, 0><<<NB, NT, 0, stream>>>(agg2, b2, W3, dinv, hs3, N);
    final_kernel<<<NB, NT, 0, stream>>>(hs3, esrc, rowptr, rowcnt, dinv, b3, out, N);
}